// Round 2
// baseline (639.359 us; speedup 1.0000x reference)
//
#include <hip/hip_runtime.h>
#include <hip/hip_bf16.h>

#define HWC   2128      // H*W = 38*56
#define Hf    38
#define Wfv   56
#define CINv  1024
#define FPv   512       // FEAT_PLANES
#define RNUM  512
#define NCLSv 81
#define NOUT  85        // 81 cls + 4 loc per roi
#define PARTN ((size_t)RNUM * NOUT)   // 43520 per-phpw plane

static __device__ __forceinline__ unsigned short f2bf(float f) {
  __hip_bfloat16 h = __float2bfloat16(f);
  return *reinterpret_cast<unsigned short*>(&h);
}

// ---------------------------------------------------------------------------
// Kernel 1: x_t[b][hw][f] = sum_c feat[b][c][hw] * w_new[f][c]   (bf16 out)
// ---------------------------------------------------------------------------
__global__ __launch_bounds__(256) void gemm1_kernel(
    const float* __restrict__ feat, const float* __restrict__ w_new,
    unsigned short* __restrict__ x_bf) {
  __shared__ float a_s[16][64];  // [kk][ff]
  __shared__ float b_s[16][64];  // [kk][hh]
  const int tid = threadIdx.x;
  const int hw0 = blockIdx.x * 64;
  const int f0  = blockIdx.y * 64;
  const int b   = blockIdx.z;
  const int tx = tid & 15;
  const int ty = tid >> 4;
  float acc[4][4] = {};
  const float* featb = feat + (size_t)b * CINv * HWC;
  const int a_ff = tid >> 2, a_k4 = (tid & 3) * 4;
  const int b_kk = tid >> 4, b_h4 = (tid & 15) * 4;

  for (int c0 = 0; c0 < CINv; c0 += 16) {
    float4 av = *(const float4*)(w_new + (size_t)(f0 + a_ff) * CINv + c0 + a_k4);
    float4 bv = make_float4(0.f, 0.f, 0.f, 0.f);
    const int hwi = hw0 + b_h4;
    if (hwi < HWC)
      bv = *(const float4*)(featb + (size_t)(c0 + b_kk) * HWC + hwi);
    __syncthreads();
    a_s[a_k4 + 0][a_ff] = av.x;
    a_s[a_k4 + 1][a_ff] = av.y;
    a_s[a_k4 + 2][a_ff] = av.z;
    a_s[a_k4 + 3][a_ff] = av.w;
    *(float4*)&b_s[b_kk][b_h4] = bv;
    __syncthreads();
#pragma unroll
    for (int kk = 0; kk < 16; ++kk) {
      const float4 aa = *(const float4*)&a_s[kk][tx * 4];
      const float4 bb = *(const float4*)&b_s[kk][ty * 4];
      const float af[4] = {aa.x, aa.y, aa.z, aa.w};
      const float bf[4] = {bb.x, bb.y, bb.z, bb.w};
#pragma unroll
      for (int jh = 0; jh < 4; ++jh)
#pragma unroll
        for (int jf = 0; jf < 4; ++jf)
          acc[jh][jf] = fmaf(bf[jh], af[jf], acc[jh][jf]);
    }
  }
#pragma unroll
  for (int jh = 0; jh < 4; ++jh) {
    const int hw = hw0 + ty * 4 + jh;
    if (hw < HWC) {
      ushort4 ov;
      ov.x = f2bf(acc[jh][0]);
      ov.y = f2bf(acc[jh][1]);
      ov.z = f2bf(acc[jh][2]);
      ov.w = f2bf(acc[jh][3]);
      *(ushort4*)(x_bf + ((size_t)b * HWC + hw) * FPv + f0 + tx * 4) = ov;
    }
  }
}

// ---------------------------------------------------------------------------
// Kernel 2: PSRoI pool (512-d) + GEMV -> partial[phpw][r][c]  (pure stores)
// Grid: (49, 64 roi-tiles of 8). Block 256.
// ---------------------------------------------------------------------------
__global__ __launch_bounds__(256) void pool_gemv_kernel(
    const unsigned short* __restrict__ x_bf, const float* __restrict__ rois,
    const float* __restrict__ w_score, const float* __restrict__ b_score,
    const float* __restrict__ w_bbox, const float* __restrict__ b_bbox,
    const void* __restrict__ stride_ptr, float* __restrict__ partial) {
  __shared__ float p[8][512];
  const int tid = threadIdx.x;
  const int phpw = blockIdx.x;  // 0..48
  const int ph = phpw / 7, pw = phpw % 7;
  const int r0 = blockIdx.y * 8;

  float stride_f;
  {
    const int iv = ((const int*)stride_ptr)[0];
    if (iv >= 1 && iv <= 4096) stride_f = (float)iv;
    else stride_f = ((const float*)stride_ptr)[0];
  }
  const float inv = 1.0f / stride_f;

  // ---- Phase A: pooled feature vectors (bf16 gathers, fp32 math) ----
  const int fq  = (tid & 127) * 4;   // 4 features per thread
  const int rtb = (tid >> 7) * 4;    // threads split over roi halves
  for (int rt = rtb; rt < rtb + 4; ++rt) {
    const int r = r0 + rt;
    const float* ro = rois + (size_t)r * 5;
    const int b = (int)ro[0];
    const float x1 = ro[1] * inv, y1 = ro[2] * inv;
    const float x2 = ro[3] * inv, y2 = ro[4] * inv;
    const float bwf = fmaxf(x2 - x1, 0.1f) * (1.0f / 7.0f);
    const float bhf = fmaxf(y2 - y1, 0.1f) * (1.0f / 7.0f);
    const unsigned short* xb = x_bf + (size_t)b * HWC * FPv;
    float a0 = 0.f, a1 = 0.f, a2 = 0.f, a3 = 0.f;
#pragma unroll
    for (int sy = 0; sy < 2; ++sy) {
      float yy = y1 + ((float)ph + ((float)sy + 0.5f) * 0.5f) * bhf;
      yy = fminf(fmaxf(yy, 0.f), (float)(Hf - 1));
      const float y0f = floorf(yy);
      const int y0 = (int)y0f;
      const int y1i = min(y0 + 1, Hf - 1);
      const float wy = yy - y0f;
#pragma unroll
      for (int sx = 0; sx < 2; ++sx) {
        float xx = x1 + ((float)pw + ((float)sx + 0.5f) * 0.5f) * bwf;
        xx = fminf(fmaxf(xx, 0.f), (float)(Wfv - 1));
        const float x0f = floorf(xx);
        const int x0 = (int)x0f;
        const int x1i = min(x0 + 1, Wfv - 1);
        const float wx = xx - x0f;
        const float w00 = (1.f - wy) * (1.f - wx), w01 = (1.f - wy) * wx;
        const float w10 = wy * (1.f - wx), w11 = wy * wx;
        const int pix00 = y0 * Wfv + x0,  pix01 = y0 * Wfv + x1i;
        const int pix10 = y1i * Wfv + x0, pix11 = y1i * Wfv + x1i;
#define LOAD4(PIX, U0, U1)                                        \
        uint2 U_##U0 = *(const uint2*)(xb + (size_t)(PIX) * FPv + fq);
        LOAD4(pix00, u00, _)
        LOAD4(pix01, u01, _)
        LOAD4(pix10, u10, _)
        LOAD4(pix11, u11, _)
#undef LOAD4
#define BF(U, J)                                                              \
        __uint_as_float((J) == 0 ? ((U.x & 0xffffu) << 16)                    \
                       : (J) == 1 ? (U.x & 0xffff0000u)                       \
                       : (J) == 2 ? ((U.y & 0xffffu) << 16)                   \
                                  : (U.y & 0xffff0000u))
        a0 += w00 * BF(U_u00, 0) + w01 * BF(U_u01, 0) + w10 * BF(U_u10, 0) + w11 * BF(U_u11, 0);
        a1 += w00 * BF(U_u00, 1) + w01 * BF(U_u01, 1) + w10 * BF(U_u10, 1) + w11 * BF(U_u11, 1);
        a2 += w00 * BF(U_u00, 2) + w01 * BF(U_u01, 2) + w10 * BF(U_u10, 2) + w11 * BF(U_u11, 2);
        a3 += w00 * BF(U_u00, 3) + w01 * BF(U_u01, 3) + w10 * BF(U_u10, 3) + w11 * BF(U_u11, 3);
#undef BF
      }
    }
    *(float4*)&p[rt][fq] =
        make_float4(a0 * 0.25f, a1 * 0.25f, a2 * 0.25f, a3 * 0.25f);
  }
  __syncthreads();

  // ---- Phase B: wave-cooperative GEMV; one store per (rt,c) ----
  const int lane = tid & 63;
  const int wave = tid >> 6;
  const int fb0 = lane * 4;
  for (int idx = wave; idx < 8 * NOUT; idx += 4) {
    const int rt = idx / NOUT;
    const int c = idx % NOUT;
    const float* wrow;
    float bias;
    if (c < NCLSv) {
      const int o = c * 49 + phpw;
      wrow = w_score + (size_t)o * FPv;
      bias = b_score[o];
    } else {
      const int o = (c - NCLSv) * 49 + phpw;
      wrow = w_bbox + (size_t)o * FPv;
      bias = b_bbox[o];
    }
    const float4 w0 = *(const float4*)(wrow + fb0);
    const float4 w1 = *(const float4*)(wrow + 256 + fb0);
    const float4 p0 = *(const float4*)&p[rt][fb0];
    const float4 p1 = *(const float4*)&p[rt][256 + fb0];
    float s = w0.x * p0.x + w0.y * p0.y + w0.z * p0.z + w0.w * p0.w +
              w1.x * p1.x + w1.y * p1.y + w1.z * p1.z + w1.w * p1.w;
#pragma unroll
    for (int off = 32; off; off >>= 1) s += __shfl_xor(s, off);
    if (lane == 0)
      partial[(size_t)phpw * PARTN + (size_t)(r0 + rt) * NOUT + c] = s + bias;
  }
}

// ---------------------------------------------------------------------------
// Kernel 3: fixed-order reduction over the 49 bins -> final output layout.
// ---------------------------------------------------------------------------
__global__ __launch_bounds__(256) void reduce_kernel(
    const float* __restrict__ partial, float* __restrict__ out) {
  const int g = blockIdx.x * 256 + threadIdx.x;  // 0..43519 exactly
  float s = 0.f;
  for (int b = 0; b < 49; ++b) s += partial[(size_t)b * PARTN + g];
  s *= (1.0f / 49.0f);
  const int r = g / NOUT;
  const int cc = g - r * NOUT;
  if (cc < NCLSv)
    out[(size_t)r * NCLSv + cc] = s;
  else
    out[(size_t)RNUM * NCLSv + (size_t)r * 4 + (cc - NCLSv)] = s;
}

// ---------------------------------------------------------------------------
extern "C" void kernel_launch(void* const* d_in, const int* in_sizes, int n_in,
                              void* d_out, int out_size, void* d_ws,
                              size_t ws_size, hipStream_t stream) {
  const float* rois    = (const float*)d_in[0];
  const float* feat    = (const float*)d_in[1];
  const float* w_new   = (const float*)d_in[2];
  const float* w_score = (const float*)d_in[3];
  const float* b_score = (const float*)d_in[4];
  const float* w_bbox  = (const float*)d_in[5];
  const float* b_bbox  = (const float*)d_in[6];
  const void*  stridep = d_in[7];
  float* out = (float*)d_out;

  unsigned short* x_bf = (unsigned short*)d_ws;              // 2*2128*512*2 = 4.36 MB
  float* partial = (float*)((char*)d_ws + (size_t)2 * HWC * FPv * 2);  // 49*43520*4 = 8.53 MB

  {
    dim3 grid((HWC + 63) / 64, FPv / 64, 2);
    gemm1_kernel<<<grid, 256, 0, stream>>>(feat, w_new, x_bf);
  }
  {
    dim3 grid(49, RNUM / 8);
    pool_gemv_kernel<<<grid, 256, 0, stream>>>(x_bf, rois, w_score, b_score,
                                               w_bbox, b_bbox, stridep, partial);
  }
  {
    dim3 grid((RNUM * NOUT) / 256);  // 43520/256 = 170 exact
    reduce_kernel<<<grid, 256, 0, stream>>>(partial, out);
  }
}

// Round 3
// 197.610 us; speedup vs baseline: 3.2355x; 3.2355x over previous
//
#include <hip/hip_runtime.h>
#include <hip/hip_bf16.h>

#define HWC   2128      // H*W = 38*56
#define Hf    38
#define Wfv   56
#define CINv  1024
#define FPv   512       // FEAT_PLANES
#define RNUM  512
#define NCLSv 81
#define NOUT  85        // 81 cls + 4 loc
#define NBIN  49
#define KTOT  (NBIN * FPv)            // 25088
#define PARTN ((size_t)RNUM * NOUT)   // 43520

typedef short bf16x8 __attribute__((ext_vector_type(8)));
typedef float f32x4 __attribute__((ext_vector_type(4)));

static __device__ __forceinline__ unsigned short f2bf(float f) {
  __hip_bfloat16 h = __float2bfloat16(f);
  return *reinterpret_cast<unsigned short*>(&h);
}
static __device__ __forceinline__ float bflo(unsigned u) {
  return __uint_as_float((u & 0xffffu) << 16);
}
static __device__ __forceinline__ float bfhi(unsigned u) {
  return __uint_as_float(u & 0xffff0000u);
}

// ---------------------------------------------------------------------------
// Kernel 0: prepack Wt[96][25088] bf16 (rows 85..95 zero) + bias_mean[96].
// Wt[c][bin*512+f] = (c<81 ? w_score[(c*49+bin)][f] : w_bbox[(c-81)*49+bin][f])
// ---------------------------------------------------------------------------
__global__ __launch_bounds__(256) void prepack_kernel(
    const float* __restrict__ w_score, const float* __restrict__ b_score,
    const float* __restrict__ w_bbox, const float* __restrict__ b_bbox,
    unsigned short* __restrict__ Wt, float* __restrict__ bias_mean) {
  const int c = blockIdx.x;  // 0..95
  if (blockIdx.y == 0 && threadIdx.x == 0) {
    float s = 0.f;
    if (c < NCLSv)
      for (int b = 0; b < NBIN; ++b) s += b_score[c * NBIN + b];
    else if (c < NOUT)
      for (int b = 0; b < NBIN; ++b) s += b_bbox[(c - NCLSv) * NBIN + b];
    bias_mean[c] = s * (1.0f / NBIN);
  }
  const int k0 = blockIdx.y * 1024 + threadIdx.x * 4;
  if (k0 >= KTOT) return;
  const int bin = k0 >> 9, f = k0 & 511;
  float4 v = make_float4(0.f, 0.f, 0.f, 0.f);
  if (c < NCLSv)
    v = *(const float4*)(w_score + ((size_t)(c * NBIN + bin)) * FPv + f);
  else if (c < NOUT)
    v = *(const float4*)(w_bbox + ((size_t)((c - NCLSv) * NBIN + bin)) * FPv + f);
  ushort4 o;
  o.x = f2bf(v.x); o.y = f2bf(v.y); o.z = f2bf(v.z); o.w = f2bf(v.w);
  *(ushort4*)(Wt + (size_t)c * KTOT + k0) = o;
}

// ---------------------------------------------------------------------------
// Kernel 1: x_bf[b][hw][f] = sum_c feat[b][c][hw] * w_new[f][c]   (bf16 out)
// (unchanged from round 2 — proven correct)
// ---------------------------------------------------------------------------
__global__ __launch_bounds__(256) void gemm1_kernel(
    const float* __restrict__ feat, const float* __restrict__ w_new,
    unsigned short* __restrict__ x_bf) {
  __shared__ float a_s[16][64];
  __shared__ float b_s[16][64];
  const int tid = threadIdx.x;
  const int hw0 = blockIdx.x * 64;
  const int f0  = blockIdx.y * 64;
  const int b   = blockIdx.z;
  const int tx = tid & 15;
  const int ty = tid >> 4;
  float acc[4][4] = {};
  const float* featb = feat + (size_t)b * CINv * HWC;
  const int a_ff = tid >> 2, a_k4 = (tid & 3) * 4;
  const int b_kk = tid >> 4, b_h4 = (tid & 15) * 4;

  for (int c0 = 0; c0 < CINv; c0 += 16) {
    float4 av = *(const float4*)(w_new + (size_t)(f0 + a_ff) * CINv + c0 + a_k4);
    float4 bv = make_float4(0.f, 0.f, 0.f, 0.f);
    const int hwi = hw0 + b_h4;
    if (hwi < HWC)
      bv = *(const float4*)(featb + (size_t)(c0 + b_kk) * HWC + hwi);
    __syncthreads();
    a_s[a_k4 + 0][a_ff] = av.x;
    a_s[a_k4 + 1][a_ff] = av.y;
    a_s[a_k4 + 2][a_ff] = av.z;
    a_s[a_k4 + 3][a_ff] = av.w;
    *(float4*)&b_s[b_kk][b_h4] = bv;
    __syncthreads();
#pragma unroll
    for (int kk = 0; kk < 16; ++kk) {
      const float4 aa = *(const float4*)&a_s[kk][tx * 4];
      const float4 bb = *(const float4*)&b_s[kk][ty * 4];
      const float af[4] = {aa.x, aa.y, aa.z, aa.w};
      const float bf[4] = {bb.x, bb.y, bb.z, bb.w};
#pragma unroll
      for (int jh = 0; jh < 4; ++jh)
#pragma unroll
        for (int jf = 0; jf < 4; ++jf)
          acc[jh][jf] = fmaf(bf[jh], af[jf], acc[jh][jf]);
    }
  }
#pragma unroll
  for (int jh = 0; jh < 4; ++jh) {
    const int hw = hw0 + ty * 4 + jh;
    if (hw < HWC) {
      ushort4 ov;
      ov.x = f2bf(acc[jh][0]);
      ov.y = f2bf(acc[jh][1]);
      ov.z = f2bf(acc[jh][2]);
      ov.w = f2bf(acc[jh][3]);
      *(ushort4*)(x_bf + ((size_t)b * HWC + hw) * FPv + f0 + tx * 4) = ov;
    }
  }
}

// ---------------------------------------------------------------------------
// Kernel 2: PSRoI pooling over all 49 bins -> P[r][bin*512+f] (bf16 pairs).
// One block per roi; thread t owns features 2t, 2t+1.
// ---------------------------------------------------------------------------
__global__ __launch_bounds__(256) void pool_kernel(
    const unsigned short* __restrict__ x_bf, const float* __restrict__ rois,
    const void* __restrict__ stride_ptr, unsigned int* __restrict__ P_u) {
  __shared__ int ys0[14], ys1[14];
  __shared__ float wys[14];
  __shared__ int xs0[14], xs1[14];
  __shared__ float wxs[14];
  const int tid = threadIdx.x;
  const int r = blockIdx.x;
  const float* ro = rois + (size_t)r * 5;

  float stride_f;
  {
    const int iv = ((const int*)stride_ptr)[0];
    if (iv >= 1 && iv <= 4096) stride_f = (float)iv;
    else stride_f = ((const float*)stride_ptr)[0];
  }
  const float inv = 1.0f / stride_f;

  if (tid < 14) {
    const float y1v = ro[2] * inv, y2v = ro[4] * inv;
    const float bhf = fmaxf(y2v - y1v, 0.1f) * (1.0f / 7.0f);
    const int ph = tid >> 1, sy = tid & 1;
    float yy = y1v + ((float)ph + ((float)sy + 0.5f) * 0.5f) * bhf;
    yy = fminf(fmaxf(yy, 0.f), (float)(Hf - 1));
    const float y0f = floorf(yy);
    ys0[tid] = (int)y0f;
    ys1[tid] = min((int)y0f + 1, Hf - 1);
    wys[tid] = yy - y0f;
  } else if (tid >= 64 && tid < 78) {
    const int s = tid - 64;
    const float x1v = ro[1] * inv, x2v = ro[3] * inv;
    const float bwf = fmaxf(x2v - x1v, 0.1f) * (1.0f / 7.0f);
    const int pw = s >> 1, sx = s & 1;
    float xx = x1v + ((float)pw + ((float)sx + 0.5f) * 0.5f) * bwf;
    xx = fminf(fmaxf(xx, 0.f), (float)(Wfv - 1));
    const float x0f = floorf(xx);
    xs0[s] = (int)x0f;
    xs1[s] = min((int)x0f + 1, Wfv - 1);
    wxs[s] = xx - x0f;
  }
  __syncthreads();

  const int b = (int)ro[0];
  const unsigned short* xb = x_bf + (size_t)b * HWC * FPv;
  const int f2 = tid * 2;
  unsigned int* Prow = P_u + (size_t)r * (KTOT / 2);

  for (int ph = 0; ph < 7; ++ph) {
    float acc[7][2] = {};
#pragma unroll
    for (int sy = 0; sy < 2; ++sy) {
      const int ry0 = ys0[ph * 2 + sy] * Wfv;
      const int ry1 = ys1[ph * 2 + sy] * Wfv;
      const float wy = wys[ph * 2 + sy];
      const float cy = 1.f - wy;
#pragma unroll
      for (int pwsx = 0; pwsx < 14; ++pwsx) {
        const int xi0 = xs0[pwsx], xi1 = xs1[pwsx];
        const float wx = wxs[pwsx];
        const float cx = 1.f - wx;
        const unsigned u00 = *(const unsigned*)(xb + (size_t)(ry0 + xi0) * FPv + f2);
        const unsigned u01 = *(const unsigned*)(xb + (size_t)(ry0 + xi1) * FPv + f2);
        const unsigned u10 = *(const unsigned*)(xb + (size_t)(ry1 + xi0) * FPv + f2);
        const unsigned u11 = *(const unsigned*)(xb + (size_t)(ry1 + xi1) * FPv + f2);
        const float w00 = cy * cx, w01 = cy * wx, w10 = wy * cx, w11 = wy * wx;
        const int pw = pwsx >> 1;
        acc[pw][0] += w00 * bflo(u00) + w01 * bflo(u01) + w10 * bflo(u10) + w11 * bflo(u11);
        acc[pw][1] += w00 * bfhi(u00) + w01 * bfhi(u01) + w10 * bfhi(u10) + w11 * bfhi(u11);
      }
    }
#pragma unroll
    for (int pw = 0; pw < 7; ++pw) {
      const unsigned lo = f2bf(acc[pw][0] * 0.25f);
      const unsigned hi = f2bf(acc[pw][1] * 0.25f);
      Prow[(size_t)(ph * 7 + pw) * (FPv / 2) + tid] = lo | (hi << 16);
    }
  }
}

// ---------------------------------------------------------------------------
// Kernel 3: MFMA GEMM, split-K by bin. partial[bin][r][c] = P[r]·Wt[c] (bin).
// Grid (8 roi-tiles of 64, 49 bins), 256 threads = 4 waves.
// Wave w: rois [rt*64+w*16, +16), cols 0..96 (6 frags of 16).
// ---------------------------------------------------------------------------
__global__ __launch_bounds__(256) void gemm2_kernel(
    const unsigned short* __restrict__ P, const unsigned short* __restrict__ Wt,
    float* __restrict__ partial) {
  const int tid = threadIdx.x;
  const int lane = tid & 63, wid = tid >> 6;
  const int rt = blockIdx.x;   // 0..7
  const int bin = blockIdx.y;  // 0..48
  const int arow = rt * 64 + wid * 16 + (lane & 15);
  const int kbase = bin * FPv + ((lane >> 4) << 3);
  const unsigned short* Ap = P + (size_t)arow * KTOT + kbase;
  const unsigned short* Bp = Wt + (size_t)(lane & 15) * KTOT + kbase;
  f32x4 acc[6] = {};
#pragma unroll 4
  for (int ks = 0; ks < 16; ++ks) {
    const bf16x8 a = *(const bf16x8*)(Ap + ks * 32);
#pragma unroll
    for (int n = 0; n < 6; ++n) {
      const bf16x8 bfr = *(const bf16x8*)(Bp + (size_t)n * 16 * KTOT + ks * 32);
      acc[n] = __builtin_amdgcn_mfma_f32_16x16x32_bf16(a, bfr, acc[n], 0, 0, 0);
    }
  }
  // C/D: col = lane&15, row = (lane>>4)*4 + reg (rows = P/roi dim).
  const int c_lo = lane & 15;
  const int rr = rt * 64 + wid * 16 + ((lane >> 4) << 2);
  float* pb = partial + (size_t)bin * PARTN;
#pragma unroll
  for (int n = 0; n < 6; ++n) {
    const int c = n * 16 + c_lo;
    if (c < NOUT) {
#pragma unroll
      for (int reg = 0; reg < 4; ++reg)
        pb[(size_t)(rr + reg) * NOUT + c] = acc[n][reg];
    }
  }
}

// ---------------------------------------------------------------------------
// Kernel 4: fixed-order reduction over 49 bins + bias -> final layout.
// ---------------------------------------------------------------------------
__global__ __launch_bounds__(256) void reduce_kernel(
    const float* __restrict__ partial, const float* __restrict__ bias_mean,
    float* __restrict__ out) {
  const int g = blockIdx.x * 256 + threadIdx.x;  // 0..43519
  const int r = g / NOUT;
  const int cc = g - r * NOUT;
  float s = 0.f;
  for (int b = 0; b < NBIN; ++b) s += partial[(size_t)b * PARTN + g];
  s = s * (1.0f / NBIN) + bias_mean[cc];
  if (cc < NCLSv)
    out[(size_t)r * NCLSv + cc] = s;
  else
    out[(size_t)RNUM * NCLSv + (size_t)r * 4 + (cc - NCLSv)] = s;
}

// ---------------------------------------------------------------------------
extern "C" void kernel_launch(void* const* d_in, const int* in_sizes, int n_in,
                              void* d_out, int out_size, void* d_ws,
                              size_t ws_size, hipStream_t stream) {
  const float* rois    = (const float*)d_in[0];
  const float* feat    = (const float*)d_in[1];
  const float* w_new   = (const float*)d_in[2];
  const float* w_score = (const float*)d_in[3];
  const float* b_score = (const float*)d_in[4];
  const float* w_bbox  = (const float*)d_in[5];
  const float* b_bbox  = (const float*)d_in[6];
  const void*  stridep = d_in[7];
  float* out = (float*)d_out;

  // ws layout (all 256B-aligned)
  char* w = (char*)d_ws;
  unsigned short* x_bf = (unsigned short*)w;              // 4,358,144 B
  w += ((size_t)2 * HWC * FPv * 2 + 255) & ~(size_t)255;
  unsigned short* P = (unsigned short*)w;                 // 25,690,112 B
  w += ((size_t)RNUM * KTOT * 2 + 255) & ~(size_t)255;
  unsigned short* Wt = (unsigned short*)w;                // 4,816,896 B
  w += ((size_t)96 * KTOT * 2 + 255) & ~(size_t)255;
  float* partial = (float*)w;                             // 8,529,920 B
  w += ((size_t)NBIN * PARTN * 4 + 255) & ~(size_t)255;
  float* bias_mean = (float*)w;                           // 384 B

  {
    dim3 grid(96, 25);
    prepack_kernel<<<grid, 256, 0, stream>>>(w_score, b_score, w_bbox, b_bbox,
                                             Wt, bias_mean);
  }
  {
    dim3 grid((HWC + 63) / 64, FPv / 64, 2);
    gemm1_kernel<<<grid, 256, 0, stream>>>(feat, w_new, x_bf);
  }
  {
    pool_kernel<<<RNUM, 256, 0, stream>>>(x_bf, rois, stridep,
                                          (unsigned int*)P);
  }
  {
    dim3 grid(RNUM / 64, NBIN);
    gemm2_kernel<<<grid, 256, 0, stream>>>(P, Wt, partial);
  }
  {
    reduce_kernel<<<(RNUM * NOUT) / 256, 256, 0, stream>>>(partial, bias_mean,
                                                           out);
  }
}

// Round 4
// 173.659 us; speedup vs baseline: 3.6817x; 1.1379x over previous
//
#include <hip/hip_runtime.h>
#include <hip/hip_bf16.h>

#define HWC   2128      // H*W = 38*56
#define Hf    38
#define Wfv   56
#define CINv  1024
#define FPv   512       // FEAT_PLANES
#define RNUM  512
#define NCLSv 81
#define NOUT  85        // 81 cls + 4 loc
#define NBIN  49
#define KTOT  (NBIN * FPv)            // 25088
#define PARTN ((size_t)RNUM * NOUT)   // 43520

typedef short bf16x8 __attribute__((ext_vector_type(8)));
typedef float f32x4 __attribute__((ext_vector_type(4)));

static __device__ __forceinline__ unsigned short f2bf(float f) {
  __hip_bfloat16 h = __float2bfloat16(f);
  return *reinterpret_cast<unsigned short*>(&h);
}
static __device__ __forceinline__ float bflo(unsigned u) {
  return __uint_as_float((u & 0xffffu) << 16);
}
static __device__ __forceinline__ float bfhi(unsigned u) {
  return __uint_as_float(u & 0xffff0000u);
}

// ---------------------------------------------------------------------------
// Kernel 0: prepack Wt[96][25088] bf16 (rows 85..95 zero) + bias_mean[96].
// ---------------------------------------------------------------------------
__global__ __launch_bounds__(256) void prepack_kernel(
    const float* __restrict__ w_score, const float* __restrict__ b_score,
    const float* __restrict__ w_bbox, const float* __restrict__ b_bbox,
    unsigned short* __restrict__ Wt, float* __restrict__ bias_mean) {
  const int c = blockIdx.x;  // 0..95
  if (blockIdx.y == 0 && threadIdx.x == 0) {
    float s = 0.f;
    if (c < NCLSv)
      for (int b = 0; b < NBIN; ++b) s += b_score[c * NBIN + b];
    else if (c < NOUT)
      for (int b = 0; b < NBIN; ++b) s += b_bbox[(c - NCLSv) * NBIN + b];
    bias_mean[c] = s * (1.0f / NBIN);
  }
  const int k0 = blockIdx.y * 1024 + threadIdx.x * 4;
  if (k0 >= KTOT) return;
  const int bin = k0 >> 9, f = k0 & 511;
  float4 v = make_float4(0.f, 0.f, 0.f, 0.f);
  if (c < NCLSv)
    v = *(const float4*)(w_score + ((size_t)(c * NBIN + bin)) * FPv + f);
  else if (c < NOUT)
    v = *(const float4*)(w_bbox + ((size_t)((c - NCLSv) * NBIN + bin)) * FPv + f);
  ushort4 o;
  o.x = f2bf(v.x); o.y = f2bf(v.y); o.z = f2bf(v.z); o.w = f2bf(v.w);
  *(ushort4*)(Wt + (size_t)c * KTOT + k0) = o;
}

// ---------------------------------------------------------------------------
// Kernel 0b: w_new [512][1024] fp32 -> bf16 (same layout, k-contiguous).
// ---------------------------------------------------------------------------
__global__ __launch_bounds__(256) void convw_kernel(
    const float* __restrict__ w_new, unsigned short* __restrict__ wn_bf) {
  const int i = (blockIdx.x * 256 + threadIdx.x) * 4;  // < 512*1024
  const float4 v = *(const float4*)(w_new + i);
  ushort4 o;
  o.x = f2bf(v.x); o.y = f2bf(v.y); o.z = f2bf(v.z); o.w = f2bf(v.w);
  *(ushort4*)(wn_bf + i) = o;
}

// ---------------------------------------------------------------------------
// Kernel 0c: transpose+convert feat [b][c][hw] fp32 -> featT [b][hw][c] bf16.
// 32x32 LDS tiles, 256 threads (32x8), +1 pad against bank conflicts.
// ---------------------------------------------------------------------------
__global__ __launch_bounds__(256) void transpose_kernel(
    const float* __restrict__ feat, unsigned short* __restrict__ featT) {
  __shared__ float t[32][33];
  const int b = blockIdx.z;
  const int hw0 = blockIdx.x * 32, c0 = blockIdx.y * 32;
  const int tx = threadIdx.x & 31, ty = threadIdx.x >> 5;  // 32 x 8
  const float* fb = feat + (size_t)b * CINv * HWC;
  const int hw = hw0 + tx;
#pragma unroll
  for (int i = 0; i < 4; ++i) {
    const int c = c0 + ty * 4 + i;
    t[ty * 4 + i][tx] = (hw < HWC) ? fb[(size_t)c * HWC + hw] : 0.f;
  }
  __syncthreads();
  unsigned short* ft = featT + (size_t)b * HWC * CINv;
#pragma unroll
  for (int i = 0; i < 4; ++i) {
    const int hwo = hw0 + ty * 4 + i;
    if (hwo < HWC) ft[(size_t)hwo * CINv + c0 + tx] = f2bf(t[tx][ty * 4 + i]);
  }
}

// ---------------------------------------------------------------------------
// Kernel 1: MFMA GEMM: x_bf[b][hw][f] = sum_c featT[b][hw][c] * wn_bf[f][c].
// Block = 64(hw) x 64(f), 4 waves stacked on hw; same fragment recipe as
// gemm2 (verified): A rows k-contiguous, B rows k-contiguous.
// ---------------------------------------------------------------------------
__global__ __launch_bounds__(256) void gemm1_mfma_kernel(
    const unsigned short* __restrict__ featT,
    const unsigned short* __restrict__ wn_bf,
    unsigned short* __restrict__ x_bf) {
  const int tid = threadIdx.x;
  const int lane = tid & 63, wid = tid >> 6;
  const int b = blockIdx.z;
  const int f0 = blockIdx.y * 64;
  const int hwbase = blockIdx.x * 64 + wid * 16;
  const int arow = min(hwbase + (lane & 15), HWC - 1);
  const unsigned short* Ap =
      featT + ((size_t)b * HWC + arow) * CINv + ((lane >> 4) << 3);
  const unsigned short* Bp =
      wn_bf + (size_t)(f0 + (lane & 15)) * CINv + ((lane >> 4) << 3);
  f32x4 acc[4] = {};
#pragma unroll 8
  for (int k = 0; k < CINv; k += 32) {
    const bf16x8 a = *(const bf16x8*)(Ap + k);
#pragma unroll
    for (int n = 0; n < 4; ++n) {
      const bf16x8 bv = *(const bf16x8*)(Bp + (size_t)n * 16 * CINv + k);
      acc[n] = __builtin_amdgcn_mfma_f32_16x16x32_bf16(a, bv, acc[n], 0, 0, 0);
    }
  }
  // D: col = lane&15 (f), row = (lane>>4)*4 + reg (hw)
  const int c_lo = lane & 15;
  const int rbase = hwbase + ((lane >> 4) << 2);
#pragma unroll
  for (int n = 0; n < 4; ++n) {
#pragma unroll
    for (int reg = 0; reg < 4; ++reg) {
      const int hwo = rbase + reg;
      if (hwo < HWC)
        x_bf[((size_t)b * HWC + hwo) * FPv + f0 + n * 16 + c_lo] =
            f2bf(acc[n][reg]);
    }
  }
}

// ---------------------------------------------------------------------------
// Kernel 2: PSRoI pooling over all 49 bins -> P[r][bin*512+f] (bf16 pairs).
// ---------------------------------------------------------------------------
__global__ __launch_bounds__(256) void pool_kernel(
    const unsigned short* __restrict__ x_bf, const float* __restrict__ rois,
    const void* __restrict__ stride_ptr, unsigned int* __restrict__ P_u) {
  __shared__ int ys0[14], ys1[14];
  __shared__ float wys[14];
  __shared__ int xs0[14], xs1[14];
  __shared__ float wxs[14];
  const int tid = threadIdx.x;
  const int r = blockIdx.x;
  const float* ro = rois + (size_t)r * 5;

  float stride_f;
  {
    const int iv = ((const int*)stride_ptr)[0];
    if (iv >= 1 && iv <= 4096) stride_f = (float)iv;
    else stride_f = ((const float*)stride_ptr)[0];
  }
  const float inv = 1.0f / stride_f;

  if (tid < 14) {
    const float y1v = ro[2] * inv, y2v = ro[4] * inv;
    const float bhf = fmaxf(y2v - y1v, 0.1f) * (1.0f / 7.0f);
    const int ph = tid >> 1, sy = tid & 1;
    float yy = y1v + ((float)ph + ((float)sy + 0.5f) * 0.5f) * bhf;
    yy = fminf(fmaxf(yy, 0.f), (float)(Hf - 1));
    const float y0f = floorf(yy);
    ys0[tid] = (int)y0f;
    ys1[tid] = min((int)y0f + 1, Hf - 1);
    wys[tid] = yy - y0f;
  } else if (tid >= 64 && tid < 78) {
    const int s = tid - 64;
    const float x1v = ro[1] * inv, x2v = ro[3] * inv;
    const float bwf = fmaxf(x2v - x1v, 0.1f) * (1.0f / 7.0f);
    const int pw = s >> 1, sx = s & 1;
    float xx = x1v + ((float)pw + ((float)sx + 0.5f) * 0.5f) * bwf;
    xx = fminf(fmaxf(xx, 0.f), (float)(Wfv - 1));
    const float x0f = floorf(xx);
    xs0[s] = (int)x0f;
    xs1[s] = min((int)x0f + 1, Wfv - 1);
    wxs[s] = xx - x0f;
  }
  __syncthreads();

  const int b = (int)ro[0];
  const unsigned short* xb = x_bf + (size_t)b * HWC * FPv;
  const int f2 = tid * 2;
  unsigned int* Prow = P_u + (size_t)r * (KTOT / 2);

  for (int ph = 0; ph < 7; ++ph) {
    float acc[7][2] = {};
#pragma unroll
    for (int sy = 0; sy < 2; ++sy) {
      const int ry0 = ys0[ph * 2 + sy] * Wfv;
      const int ry1 = ys1[ph * 2 + sy] * Wfv;
      const float wy = wys[ph * 2 + sy];
      const float cy = 1.f - wy;
#pragma unroll
      for (int pwsx = 0; pwsx < 14; ++pwsx) {
        const int xi0 = xs0[pwsx], xi1 = xs1[pwsx];
        const float wx = wxs[pwsx];
        const float cx = 1.f - wx;
        const unsigned u00 = *(const unsigned*)(xb + (size_t)(ry0 + xi0) * FPv + f2);
        const unsigned u01 = *(const unsigned*)(xb + (size_t)(ry0 + xi1) * FPv + f2);
        const unsigned u10 = *(const unsigned*)(xb + (size_t)(ry1 + xi0) * FPv + f2);
        const unsigned u11 = *(const unsigned*)(xb + (size_t)(ry1 + xi1) * FPv + f2);
        const float w00 = cy * cx, w01 = cy * wx, w10 = wy * cx, w11 = wy * wx;
        const int pw = pwsx >> 1;
        acc[pw][0] += w00 * bflo(u00) + w01 * bflo(u01) + w10 * bflo(u10) + w11 * bflo(u11);
        acc[pw][1] += w00 * bfhi(u00) + w01 * bfhi(u01) + w10 * bfhi(u10) + w11 * bfhi(u11);
      }
    }
#pragma unroll
    for (int pw = 0; pw < 7; ++pw) {
      const unsigned lo = f2bf(acc[pw][0] * 0.25f);
      const unsigned hi = f2bf(acc[pw][1] * 0.25f);
      Prow[(size_t)(ph * 7 + pw) * (FPv / 2) + tid] = lo | (hi << 16);
    }
  }
}

// ---------------------------------------------------------------------------
// Kernel 3: MFMA GEMM, split-K by bin. partial[bin][r][c] = P[r]·Wt[c] (bin).
// ---------------------------------------------------------------------------
__global__ __launch_bounds__(256) void gemm2_kernel(
    const unsigned short* __restrict__ P, const unsigned short* __restrict__ Wt,
    float* __restrict__ partial) {
  const int tid = threadIdx.x;
  const int lane = tid & 63, wid = tid >> 6;
  const int rt = blockIdx.x;   // 0..7
  const int bin = blockIdx.y;  // 0..48
  const int arow = rt * 64 + wid * 16 + (lane & 15);
  const int kbase = bin * FPv + ((lane >> 4) << 3);
  const unsigned short* Ap = P + (size_t)arow * KTOT + kbase;
  const unsigned short* Bp = Wt + (size_t)(lane & 15) * KTOT + kbase;
  f32x4 acc[6] = {};
#pragma unroll 4
  for (int ks = 0; ks < 16; ++ks) {
    const bf16x8 a = *(const bf16x8*)(Ap + ks * 32);
#pragma unroll
    for (int n = 0; n < 6; ++n) {
      const bf16x8 bfr = *(const bf16x8*)(Bp + (size_t)n * 16 * KTOT + ks * 32);
      acc[n] = __builtin_amdgcn_mfma_f32_16x16x32_bf16(a, bfr, acc[n], 0, 0, 0);
    }
  }
  const int c_lo = lane & 15;
  const int rr = rt * 64 + wid * 16 + ((lane >> 4) << 2);
  float* pb = partial + (size_t)bin * PARTN;
#pragma unroll
  for (int n = 0; n < 6; ++n) {
    const int c = n * 16 + c_lo;
    if (c < NOUT) {
#pragma unroll
      for (int reg = 0; reg < 4; ++reg)
        pb[(size_t)(rr + reg) * NOUT + c] = acc[n][reg];
    }
  }
}

// ---------------------------------------------------------------------------
// Kernel 4: fixed-order reduction over 49 bins + bias -> final layout.
// ---------------------------------------------------------------------------
__global__ __launch_bounds__(256) void reduce_kernel(
    const float* __restrict__ partial, const float* __restrict__ bias_mean,
    float* __restrict__ out) {
  const int g = blockIdx.x * 256 + threadIdx.x;  // 0..43519
  const int r = g / NOUT;
  const int cc = g - r * NOUT;
  float s = 0.f;
  for (int b = 0; b < NBIN; ++b) s += partial[(size_t)b * PARTN + g];
  s = s * (1.0f / NBIN) + bias_mean[cc];
  if (cc < NCLSv)
    out[(size_t)r * NCLSv + cc] = s;
  else
    out[(size_t)RNUM * NCLSv + (size_t)r * 4 + (cc - NCLSv)] = s;
}

// ---------------------------------------------------------------------------
extern "C" void kernel_launch(void* const* d_in, const int* in_sizes, int n_in,
                              void* d_out, int out_size, void* d_ws,
                              size_t ws_size, hipStream_t stream) {
  const float* rois    = (const float*)d_in[0];
  const float* feat    = (const float*)d_in[1];
  const float* w_new   = (const float*)d_in[2];
  const float* w_score = (const float*)d_in[3];
  const float* b_score = (const float*)d_in[4];
  const float* w_bbox  = (const float*)d_in[5];
  const float* b_bbox  = (const float*)d_in[6];
  const void*  stridep = d_in[7];
  float* out = (float*)d_out;

  // ws layout (256B-aligned). featT (dead after gemm1) aliases partial.
  char* w = (char*)d_ws;
  unsigned short* x_bf = (unsigned short*)w;               // 4,358,144 B
  w += ((size_t)2 * HWC * FPv * 2 + 255) & ~(size_t)255;
  unsigned short* P = (unsigned short*)w;                  // 25,690,112 B
  w += ((size_t)RNUM * KTOT * 2 + 255) & ~(size_t)255;
  unsigned short* Wt = (unsigned short*)w;                 // 4,816,896 B
  w += ((size_t)96 * KTOT * 2 + 255) & ~(size_t)255;
  char* shared_blk = w;                                    // max(featT, partial)
  unsigned short* featT = (unsigned short*)shared_blk;     // 8,716,288 B
  float* partial = (float*)shared_blk;                     // 8,529,920 B
  w += ((size_t)2 * HWC * CINv * 2 + 255) & ~(size_t)255;
  unsigned short* wn_bf = (unsigned short*)w;              // 1,048,576 B
  w += ((size_t)FPv * CINv * 2 + 255) & ~(size_t)255;
  float* bias_mean = (float*)w;                            // 384 B

  {
    dim3 grid(96, 25);
    prepack_kernel<<<grid, 256, 0, stream>>>(w_score, b_score, w_bbox, b_bbox,
                                             Wt, bias_mean);
  }
  {
    convw_kernel<<<(FPv * CINv) / 1024, 256, 0, stream>>>(w_new, wn_bf);
  }
  {
    dim3 grid((HWC + 31) / 32, CINv / 32, 2);
    transpose_kernel<<<grid, 256, 0, stream>>>(feat, featT);
  }
  {
    dim3 grid((HWC + 63) / 64, FPv / 64, 2);
    gemm1_mfma_kernel<<<grid, 256, 0, stream>>>(featT, wn_bf, x_bf);
  }
  {
    pool_kernel<<<RNUM, 256, 0, stream>>>(x_bf, rois, stridep,
                                          (unsigned int*)P);
  }
  {
    dim3 grid(RNUM / 64, NBIN);
    gemm2_kernel<<<grid, 256, 0, stream>>>(P, Wt, partial);
  }
  {
    reduce_kernel<<<(RNUM * NOUT) / 256, 256, 0, stream>>>(partial, bias_mean,
                                                           out);
  }
}

// Round 5
// 128.636 us; speedup vs baseline: 4.9703x; 1.3500x over previous
//
#include <hip/hip_runtime.h>
#include <hip/hip_bf16.h>

#define HWC   2128      // H*W = 38*56
#define Hf    38
#define Wfv   56
#define CINv  1024
#define FPv   512       // FEAT_PLANES
#define RNUM  512
#define NCLSv 81
#define NOUT  85        // 81 cls + 4 loc
#define NBIN  49
#define KTOT  (NBIN * FPv)            // 25088
#define PARTN ((size_t)RNUM * NOUT)   // 43520

typedef short bf16x8 __attribute__((ext_vector_type(8)));
typedef float f32x4 __attribute__((ext_vector_type(4)));

static __device__ __forceinline__ unsigned short f2bf(float f) {
  __hip_bfloat16 h = __float2bfloat16(f);
  return *reinterpret_cast<unsigned short*>(&h);
}
static __device__ __forceinline__ float bflo(unsigned u) {
  return __uint_as_float((u & 0xffffu) << 16);
}
static __device__ __forceinline__ float bfhi(unsigned u) {
  return __uint_as_float(u & 0xffff0000u);
}

// ---------------------------------------------------------------------------
// Kernel 0: prepack Wt[96][25088] bf16 (rows 85..95 zero) + bias_mean[96].
// ---------------------------------------------------------------------------
__global__ __launch_bounds__(256) void prepack_kernel(
    const float* __restrict__ w_score, const float* __restrict__ b_score,
    const float* __restrict__ w_bbox, const float* __restrict__ b_bbox,
    unsigned short* __restrict__ Wt, float* __restrict__ bias_mean) {
  const int c = blockIdx.x;  // 0..95
  if (blockIdx.y == 0 && threadIdx.x == 0) {
    float s = 0.f;
    if (c < NCLSv)
      for (int b = 0; b < NBIN; ++b) s += b_score[c * NBIN + b];
    else if (c < NOUT)
      for (int b = 0; b < NBIN; ++b) s += b_bbox[(c - NCLSv) * NBIN + b];
    bias_mean[c] = s * (1.0f / NBIN);
  }
  const int k0 = blockIdx.y * 1024 + threadIdx.x * 4;
  if (k0 >= KTOT) return;
  const int bin = k0 >> 9, f = k0 & 511;
  float4 v = make_float4(0.f, 0.f, 0.f, 0.f);
  if (c < NCLSv)
    v = *(const float4*)(w_score + ((size_t)(c * NBIN + bin)) * FPv + f);
  else if (c < NOUT)
    v = *(const float4*)(w_bbox + ((size_t)((c - NCLSv) * NBIN + bin)) * FPv + f);
  ushort4 o;
  o.x = f2bf(v.x); o.y = f2bf(v.y); o.z = f2bf(v.z); o.w = f2bf(v.w);
  *(ushort4*)(Wt + (size_t)c * KTOT + k0) = o;
}

// ---------------------------------------------------------------------------
// Kernel 0b: w_new [512][1024] fp32 -> bf16 (same layout, k-contiguous).
// ---------------------------------------------------------------------------
__global__ __launch_bounds__(256) void convw_kernel(
    const float* __restrict__ w_new, unsigned short* __restrict__ wn_bf) {
  const int i = (blockIdx.x * 256 + threadIdx.x) * 4;  // < 512*1024
  const float4 v = *(const float4*)(w_new + i);
  ushort4 o;
  o.x = f2bf(v.x); o.y = f2bf(v.y); o.z = f2bf(v.z); o.w = f2bf(v.w);
  *(ushort4*)(wn_bf + i) = o;
}

// ---------------------------------------------------------------------------
// Kernel 0c: transpose+convert feat [b][c][hw] fp32 -> featT [b][hw][c] bf16.
// ---------------------------------------------------------------------------
__global__ __launch_bounds__(256) void transpose_kernel(
    const float* __restrict__ feat, unsigned short* __restrict__ featT) {
  __shared__ float t[32][33];
  const int b = blockIdx.z;
  const int hw0 = blockIdx.x * 32, c0 = blockIdx.y * 32;
  const int tx = threadIdx.x & 31, ty = threadIdx.x >> 5;  // 32 x 8
  const float* fb = feat + (size_t)b * CINv * HWC;
  const int hw = hw0 + tx;
#pragma unroll
  for (int i = 0; i < 4; ++i) {
    const int c = c0 + ty * 4 + i;
    t[ty * 4 + i][tx] = (hw < HWC) ? fb[(size_t)c * HWC + hw] : 0.f;
  }
  __syncthreads();
  unsigned short* ft = featT + (size_t)b * HWC * CINv;
#pragma unroll
  for (int i = 0; i < 4; ++i) {
    const int hwo = hw0 + ty * 4 + i;
    if (hwo < HWC) ft[(size_t)hwo * CINv + c0 + tx] = f2bf(t[tx][ty * 4 + i]);
  }
}

// ---------------------------------------------------------------------------
// Kernel 1: MFMA GEMM: x_bf[b][hw][f] = sum_c featT[b][hw][c] * wn_bf[f][c].
// ---------------------------------------------------------------------------
__global__ __launch_bounds__(256) void gemm1_mfma_kernel(
    const unsigned short* __restrict__ featT,
    const unsigned short* __restrict__ wn_bf,
    unsigned short* __restrict__ x_bf) {
  const int tid = threadIdx.x;
  const int lane = tid & 63, wid = tid >> 6;
  const int b = blockIdx.z;
  const int f0 = blockIdx.y * 64;
  const int hwbase = blockIdx.x * 64 + wid * 16;
  const int arow = min(hwbase + (lane & 15), HWC - 1);
  const unsigned short* Ap =
      featT + ((size_t)b * HWC + arow) * CINv + ((lane >> 4) << 3);
  const unsigned short* Bp =
      wn_bf + (size_t)(f0 + (lane & 15)) * CINv + ((lane >> 4) << 3);
  f32x4 acc[4] = {};
#pragma unroll 8
  for (int k = 0; k < CINv; k += 32) {
    const bf16x8 a = *(const bf16x8*)(Ap + k);
#pragma unroll
    for (int n = 0; n < 4; ++n) {
      const bf16x8 bv = *(const bf16x8*)(Bp + (size_t)n * 16 * CINv + k);
      acc[n] = __builtin_amdgcn_mfma_f32_16x16x32_bf16(a, bv, acc[n], 0, 0, 0);
    }
  }
  const int c_lo = lane & 15;
  const int rbase = hwbase + ((lane >> 4) << 2);
#pragma unroll
  for (int n = 0; n < 4; ++n) {
#pragma unroll
    for (int reg = 0; reg < 4; ++reg) {
      const int hwo = rbase + reg;
      if (hwo < HWC)
        x_bf[((size_t)b * HWC + hwo) * FPv + f0 + n * 16 + c_lo] =
            f2bf(acc[n][reg]);
    }
  }
}

// ---------------------------------------------------------------------------
// Kernel 2: PSRoI pooling -> P[r][bin*512+f] (bf16 pairs).
// Grid (512 rois, 7 ph) for occupancy; block 256 threads = 512 features.
// Per block: 2 sy rows x 14 (pw,sx) samples, acc[7 pw][2 feats].
// ---------------------------------------------------------------------------
__global__ __launch_bounds__(256) void pool_kernel(
    const unsigned short* __restrict__ x_bf, const float* __restrict__ rois,
    const void* __restrict__ stride_ptr, unsigned int* __restrict__ P_u) {
  __shared__ int ys0[2], ys1[2];
  __shared__ float wys[2];
  __shared__ int xs0[14], xs1[14];
  __shared__ float wxs[14];
  const int tid = threadIdx.x;
  const int r = blockIdx.x;
  const int ph = blockIdx.y;  // 0..6
  const float* ro = rois + (size_t)r * 5;

  float stride_f;
  {
    const int iv = ((const int*)stride_ptr)[0];
    if (iv >= 1 && iv <= 4096) stride_f = (float)iv;
    else stride_f = ((const float*)stride_ptr)[0];
  }
  const float inv = 1.0f / stride_f;

  if (tid < 2) {
    const float y1v = ro[2] * inv, y2v = ro[4] * inv;
    const float bhf = fmaxf(y2v - y1v, 0.1f) * (1.0f / 7.0f);
    const int sy = tid;
    float yy = y1v + ((float)ph + ((float)sy + 0.5f) * 0.5f) * bhf;
    yy = fminf(fmaxf(yy, 0.f), (float)(Hf - 1));
    const float y0f = floorf(yy);
    ys0[tid] = (int)y0f;
    ys1[tid] = min((int)y0f + 1, Hf - 1);
    wys[tid] = yy - y0f;
  } else if (tid >= 64 && tid < 78) {
    const int s = tid - 64;
    const float x1v = ro[1] * inv, x2v = ro[3] * inv;
    const float bwf = fmaxf(x2v - x1v, 0.1f) * (1.0f / 7.0f);
    const int pw = s >> 1, sx = s & 1;
    float xx = x1v + ((float)pw + ((float)sx + 0.5f) * 0.5f) * bwf;
    xx = fminf(fmaxf(xx, 0.f), (float)(Wfv - 1));
    const float x0f = floorf(xx);
    xs0[s] = (int)x0f;
    xs1[s] = min((int)x0f + 1, Wfv - 1);
    wxs[s] = xx - x0f;
  }
  __syncthreads();

  const int b = (int)ro[0];
  const unsigned short* xb = x_bf + (size_t)b * HWC * FPv;
  const int f2 = tid * 2;

  float acc[7][2] = {};
#pragma unroll
  for (int sy = 0; sy < 2; ++sy) {
    const int ry0 = ys0[sy] * Wfv;
    const int ry1 = ys1[sy] * Wfv;
    const float wy = wys[sy];
    const float cy = 1.f - wy;
#pragma unroll
    for (int pwsx = 0; pwsx < 14; ++pwsx) {
      const int xi0 = xs0[pwsx], xi1 = xs1[pwsx];
      const float wx = wxs[pwsx];
      const float cx = 1.f - wx;
      const unsigned u00 = *(const unsigned*)(xb + (size_t)(ry0 + xi0) * FPv + f2);
      const unsigned u01 = *(const unsigned*)(xb + (size_t)(ry0 + xi1) * FPv + f2);
      const unsigned u10 = *(const unsigned*)(xb + (size_t)(ry1 + xi0) * FPv + f2);
      const unsigned u11 = *(const unsigned*)(xb + (size_t)(ry1 + xi1) * FPv + f2);
      const float w00 = cy * cx, w01 = cy * wx, w10 = wy * cx, w11 = wy * wx;
      const int pw = pwsx >> 1;
      acc[pw][0] += w00 * bflo(u00) + w01 * bflo(u01) + w10 * bflo(u10) + w11 * bflo(u11);
      acc[pw][1] += w00 * bfhi(u00) + w01 * bfhi(u01) + w10 * bfhi(u10) + w11 * bfhi(u11);
    }
  }
  unsigned int* Prow = P_u + (size_t)r * (KTOT / 2);
#pragma unroll
  for (int pw = 0; pw < 7; ++pw) {
    const unsigned lo = f2bf(acc[pw][0] * 0.25f);
    const unsigned hi = f2bf(acc[pw][1] * 0.25f);
    Prow[(size_t)(ph * 7 + pw) * (FPv / 2) + tid] = lo | (hi << 16);
  }
}

// ---------------------------------------------------------------------------
// Kernel 3: MFMA GEMM, split-K by bin. partial[bin][r][c] = P[r]·Wt[c] (bin).
// ---------------------------------------------------------------------------
__global__ __launch_bounds__(256) void gemm2_kernel(
    const unsigned short* __restrict__ P, const unsigned short* __restrict__ Wt,
    float* __restrict__ partial) {
  const int tid = threadIdx.x;
  const int lane = tid & 63, wid = tid >> 6;
  const int rt = blockIdx.x;   // 0..7
  const int bin = blockIdx.y;  // 0..48
  const int arow = rt * 64 + wid * 16 + (lane & 15);
  const int kbase = bin * FPv + ((lane >> 4) << 3);
  const unsigned short* Ap = P + (size_t)arow * KTOT + kbase;
  const unsigned short* Bp = Wt + (size_t)(lane & 15) * KTOT + kbase;
  f32x4 acc[6] = {};
#pragma unroll 4
  for (int ks = 0; ks < 16; ++ks) {
    const bf16x8 a = *(const bf16x8*)(Ap + ks * 32);
#pragma unroll
    for (int n = 0; n < 6; ++n) {
      const bf16x8 bfr = *(const bf16x8*)(Bp + (size_t)n * 16 * KTOT + ks * 32);
      acc[n] = __builtin_amdgcn_mfma_f32_16x16x32_bf16(a, bfr, acc[n], 0, 0, 0);
    }
  }
  const int c_lo = lane & 15;
  const int rr = rt * 64 + wid * 16 + ((lane >> 4) << 2);
  float* pb = partial + (size_t)bin * PARTN;
#pragma unroll
  for (int n = 0; n < 6; ++n) {
    const int c = n * 16 + c_lo;
    if (c < NOUT) {
#pragma unroll
      for (int reg = 0; reg < 4; ++reg)
        pb[(size_t)(rr + reg) * NOUT + c] = acc[n][reg];
    }
  }
}

// ---------------------------------------------------------------------------
// Kernel 4: fixed-order reduction over 49 bins + bias -> final layout.
// ---------------------------------------------------------------------------
__global__ __launch_bounds__(256) void reduce_kernel(
    const float* __restrict__ partial, const float* __restrict__ bias_mean,
    float* __restrict__ out) {
  const int g = blockIdx.x * 256 + threadIdx.x;  // 0..43519
  const int r = g / NOUT;
  const int cc = g - r * NOUT;
  float s = 0.f;
  for (int b = 0; b < NBIN; ++b) s += partial[(size_t)b * PARTN + g];
  s = s * (1.0f / NBIN) + bias_mean[cc];
  if (cc < NCLSv)
    out[(size_t)r * NCLSv + cc] = s;
  else
    out[(size_t)RNUM * NCLSv + (size_t)r * 4 + (cc - NCLSv)] = s;
}

// ---------------------------------------------------------------------------
extern "C" void kernel_launch(void* const* d_in, const int* in_sizes, int n_in,
                              void* d_out, int out_size, void* d_ws,
                              size_t ws_size, hipStream_t stream) {
  const float* rois    = (const float*)d_in[0];
  const float* feat    = (const float*)d_in[1];
  const float* w_new   = (const float*)d_in[2];
  const float* w_score = (const float*)d_in[3];
  const float* b_score = (const float*)d_in[4];
  const float* w_bbox  = (const float*)d_in[5];
  const float* b_bbox  = (const float*)d_in[6];
  const void*  stridep = d_in[7];
  float* out = (float*)d_out;

  // ws layout (256B-aligned). featT (dead after gemm1) aliases partial.
  char* w = (char*)d_ws;
  unsigned short* x_bf = (unsigned short*)w;               // 4,358,144 B
  w += ((size_t)2 * HWC * FPv * 2 + 255) & ~(size_t)255;
  unsigned short* P = (unsigned short*)w;                  // 25,690,112 B
  w += ((size_t)RNUM * KTOT * 2 + 255) & ~(size_t)255;
  unsigned short* Wt = (unsigned short*)w;                 // 4,816,896 B
  w += ((size_t)96 * KTOT * 2 + 255) & ~(size_t)255;
  char* shared_blk = w;                                    // max(featT, partial)
  unsigned short* featT = (unsigned short*)shared_blk;     // 8,716,288 B
  float* partial = (float*)shared_blk;                     // 8,529,920 B
  w += ((size_t)2 * HWC * CINv * 2 + 255) & ~(size_t)255;
  unsigned short* wn_bf = (unsigned short*)w;              // 1,048,576 B
  w += ((size_t)FPv * CINv * 2 + 255) & ~(size_t)255;
  float* bias_mean = (float*)w;                            // 384 B

  {
    dim3 grid(96, 25);
    prepack_kernel<<<grid, 256, 0, stream>>>(w_score, b_score, w_bbox, b_bbox,
                                             Wt, bias_mean);
  }
  {
    convw_kernel<<<(FPv * CINv) / 1024, 256, 0, stream>>>(w_new, wn_bf);
  }
  {
    dim3 grid((HWC + 31) / 32, CINv / 32, 2);
    transpose_kernel<<<grid, 256, 0, stream>>>(feat, featT);
  }
  {
    dim3 grid((HWC + 63) / 64, FPv / 64, 2);
    gemm1_mfma_kernel<<<grid, 256, 0, stream>>>(featT, wn_bf, x_bf);
  }
  {
    dim3 grid(RNUM, 7);
    pool_kernel<<<grid, 256, 0, stream>>>(x_bf, rois, stridep,
                                          (unsigned int*)P);
  }
  {
    dim3 grid(RNUM / 64, NBIN);
    gemm2_kernel<<<grid, 256, 0, stream>>>(P, Wt, partial);
  }
  {
    reduce_kernel<<<(RNUM * NOUT) / 256, 256, 0, stream>>>(partial, bias_mean,
                                                           out);
  }
}

// Round 6
// 107.564 us; speedup vs baseline: 5.9440x; 1.1959x over previous
//
#include <hip/hip_runtime.h>
#include <hip/hip_bf16.h>

#define HWC   2128      // H*W = 38*56
#define Hf    38
#define Wfv   56
#define CINv  1024
#define FPv   512       // FEAT_PLANES
#define RNUM  512
#define NCLSv 81
#define NOUT  85        // 81 cls + 4 loc
#define NBIN  49
#define KTOT  (NBIN * FPv)            // 25088
#define PARTN ((size_t)RNUM * NOUT)   // 43520

typedef short bf16x8 __attribute__((ext_vector_type(8)));
typedef float f32x4 __attribute__((ext_vector_type(4)));

static __device__ __forceinline__ unsigned short f2bf(float f) {
  __hip_bfloat16 h = __float2bfloat16(f);
  return *reinterpret_cast<unsigned short*>(&h);
}
static __device__ __forceinline__ float bflo(unsigned u) {
  return __uint_as_float((u & 0xffffu) << 16);
}
static __device__ __forceinline__ float bfhi(unsigned u) {
  return __uint_as_float(u & 0xffff0000u);
}

// ---------------------------------------------------------------------------
// Kernel 0: prepack Wt[96][25088] bf16 (rows 85..95 zero) + bias_mean[96].
// ---------------------------------------------------------------------------
__global__ __launch_bounds__(256) void prepack_kernel(
    const float* __restrict__ w_score, const float* __restrict__ b_score,
    const float* __restrict__ w_bbox, const float* __restrict__ b_bbox,
    unsigned short* __restrict__ Wt, float* __restrict__ bias_mean) {
  const int c = blockIdx.x;  // 0..95
  if (blockIdx.y == 0 && threadIdx.x == 0) {
    float s = 0.f;
    if (c < NCLSv)
      for (int b = 0; b < NBIN; ++b) s += b_score[c * NBIN + b];
    else if (c < NOUT)
      for (int b = 0; b < NBIN; ++b) s += b_bbox[(c - NCLSv) * NBIN + b];
    bias_mean[c] = s * (1.0f / NBIN);
  }
  const int k0 = blockIdx.y * 1024 + threadIdx.x * 4;
  if (k0 >= KTOT) return;
  const int bin = k0 >> 9, f = k0 & 511;
  float4 v = make_float4(0.f, 0.f, 0.f, 0.f);
  if (c < NCLSv)
    v = *(const float4*)(w_score + ((size_t)(c * NBIN + bin)) * FPv + f);
  else if (c < NOUT)
    v = *(const float4*)(w_bbox + ((size_t)((c - NCLSv) * NBIN + bin)) * FPv + f);
  ushort4 o;
  o.x = f2bf(v.x); o.y = f2bf(v.y); o.z = f2bf(v.z); o.w = f2bf(v.w);
  *(ushort4*)(Wt + (size_t)c * KTOT + k0) = o;
}

// ---------------------------------------------------------------------------
// Kernel 0b: w_new [512][1024] fp32 -> bf16 (same layout, k-contiguous).
// ---------------------------------------------------------------------------
__global__ __launch_bounds__(256) void convw_kernel(
    const float* __restrict__ w_new, unsigned short* __restrict__ wn_bf) {
  const int i = (blockIdx.x * 256 + threadIdx.x) * 4;  // < 512*1024
  const float4 v = *(const float4*)(w_new + i);
  ushort4 o;
  o.x = f2bf(v.x); o.y = f2bf(v.y); o.z = f2bf(v.z); o.w = f2bf(v.w);
  *(ushort4*)(wn_bf + i) = o;
}

// ---------------------------------------------------------------------------
// Kernel 0c: transpose+convert feat [b][c][hw] fp32 -> featT [b][hw][c] bf16.
// ---------------------------------------------------------------------------
__global__ __launch_bounds__(256) void transpose_kernel(
    const float* __restrict__ feat, unsigned short* __restrict__ featT) {
  __shared__ float t[32][33];
  const int b = blockIdx.z;
  const int hw0 = blockIdx.x * 32, c0 = blockIdx.y * 32;
  const int tx = threadIdx.x & 31, ty = threadIdx.x >> 5;  // 32 x 8
  const float* fb = feat + (size_t)b * CINv * HWC;
  const int hw = hw0 + tx;
#pragma unroll
  for (int i = 0; i < 4; ++i) {
    const int c = c0 + ty * 4 + i;
    t[ty * 4 + i][tx] = (hw < HWC) ? fb[(size_t)c * HWC + hw] : 0.f;
  }
  __syncthreads();
  unsigned short* ft = featT + (size_t)b * HWC * CINv;
#pragma unroll
  for (int i = 0; i < 4; ++i) {
    const int hwo = hw0 + ty * 4 + i;
    if (hwo < HWC) ft[(size_t)hwo * CINv + c0 + tx] = f2bf(t[tx][ty * 4 + i]);
  }
}

// ---------------------------------------------------------------------------
// Kernel 1: MFMA GEMM: x_bf[b][hw][f] = sum_c featT[b][hw][c] * wn_bf[f][c].
// v2: K-chunk 128; B tile staged in LDS (issue-early/write-late dbuf);
// A fragments prefetched one chunk ahead in registers.
// ---------------------------------------------------------------------------
#define BSTRIDE 136  // 128 + 8 pad (elems); keeps b128 reads at bank floor
__global__ __launch_bounds__(256) void gemm1_mfma_kernel(
    const unsigned short* __restrict__ featT,
    const unsigned short* __restrict__ wn_bf,
    unsigned short* __restrict__ x_bf) {
  __shared__ unsigned short Bs[64 * BSTRIDE];
  const int tid = threadIdx.x;
  const int lane = tid & 63, wid = tid >> 6;
  const int b = blockIdx.z;
  const int f0 = blockIdx.y * 64;
  const int hwbase = blockIdx.x * 64 + wid * 16;
  const int arow = min(hwbase + (lane & 15), HWC - 1);
  const int fr_f = lane & 15;
  const int fr_k = (lane >> 4) << 3;
  const unsigned short* Ap = featT + ((size_t)b * HWC + arow) * CINv + fr_k;
  // B staging map: thread t -> row sr, elem chunks sc + i*32 (i=0..3)
  const int sr = tid >> 2;
  const int sc = (tid & 3) * 8;
  const unsigned short* Bg = wn_bf + (size_t)(f0 + sr) * CINv + sc;

  uint4 breg[4];
  bf16x8 aCur[4], aNxt[4];
#pragma unroll
  for (int i = 0; i < 4; ++i) breg[i] = *(const uint4*)(Bg + i * 32);
#pragma unroll
  for (int s = 0; s < 4; ++s) aCur[s] = *(const bf16x8*)(Ap + s * 32);

  f32x4 acc[4] = {};
  for (int kc = 0; kc < CINv; kc += 128) {
    __syncthreads();  // previous chunk's LDS reads complete
#pragma unroll
    for (int i = 0; i < 4; ++i)
      *(uint4*)&Bs[sr * BSTRIDE + sc + i * 32] = breg[i];
    const int kn = kc + 128;
    if (kn < CINv) {
#pragma unroll
      for (int i = 0; i < 4; ++i) breg[i] = *(const uint4*)(Bg + kn + i * 32);
#pragma unroll
      for (int s = 0; s < 4; ++s) aNxt[s] = *(const bf16x8*)(Ap + kn + s * 32);
    }
    __syncthreads();  // Bs ready
#pragma unroll
    for (int s = 0; s < 4; ++s) {
#pragma unroll
      for (int n = 0; n < 4; ++n) {
        const bf16x8 bv =
            *(const bf16x8*)&Bs[(fr_f + n * 16) * BSTRIDE + s * 32 + fr_k];
        acc[n] =
            __builtin_amdgcn_mfma_f32_16x16x32_bf16(aCur[s], bv, acc[n], 0, 0, 0);
      }
    }
#pragma unroll
    for (int s = 0; s < 4; ++s) aCur[s] = aNxt[s];
  }
  // D: col = lane&15 (f), row = (lane>>4)*4 + reg (hw)
  const int c_lo = lane & 15;
  const int rbase = hwbase + ((lane >> 4) << 2);
#pragma unroll
  for (int n = 0; n < 4; ++n) {
#pragma unroll
    for (int reg = 0; reg < 4; ++reg) {
      const int hwo = rbase + reg;
      if (hwo < HWC)
        x_bf[((size_t)b * HWC + hwo) * FPv + f0 + n * 16 + c_lo] =
            f2bf(acc[n][reg]);
    }
  }
}

// ---------------------------------------------------------------------------
// Kernel 2: PSRoI pooling -> P[r][bin*512+f] (bf16 pairs). Grid (512, 7).
// ---------------------------------------------------------------------------
__global__ __launch_bounds__(256) void pool_kernel(
    const unsigned short* __restrict__ x_bf, const float* __restrict__ rois,
    const void* __restrict__ stride_ptr, unsigned int* __restrict__ P_u) {
  __shared__ int ys0[2], ys1[2];
  __shared__ float wys[2];
  __shared__ int xs0[14], xs1[14];
  __shared__ float wxs[14];
  const int tid = threadIdx.x;
  const int r = blockIdx.x;
  const int ph = blockIdx.y;  // 0..6
  const float* ro = rois + (size_t)r * 5;

  float stride_f;
  {
    const int iv = ((const int*)stride_ptr)[0];
    if (iv >= 1 && iv <= 4096) stride_f = (float)iv;
    else stride_f = ((const float*)stride_ptr)[0];
  }
  const float inv = 1.0f / stride_f;

  if (tid < 2) {
    const float y1v = ro[2] * inv, y2v = ro[4] * inv;
    const float bhf = fmaxf(y2v - y1v, 0.1f) * (1.0f / 7.0f);
    const int sy = tid;
    float yy = y1v + ((float)ph + ((float)sy + 0.5f) * 0.5f) * bhf;
    yy = fminf(fmaxf(yy, 0.f), (float)(Hf - 1));
    const float y0f = floorf(yy);
    ys0[tid] = (int)y0f;
    ys1[tid] = min((int)y0f + 1, Hf - 1);
    wys[tid] = yy - y0f;
  } else if (tid >= 64 && tid < 78) {
    const int s = tid - 64;
    const float x1v = ro[1] * inv, x2v = ro[3] * inv;
    const float bwf = fmaxf(x2v - x1v, 0.1f) * (1.0f / 7.0f);
    const int pw = s >> 1, sx = s & 1;
    float xx = x1v + ((float)pw + ((float)sx + 0.5f) * 0.5f) * bwf;
    xx = fminf(fmaxf(xx, 0.f), (float)(Wfv - 1));
    const float x0f = floorf(xx);
    xs0[s] = (int)x0f;
    xs1[s] = min((int)x0f + 1, Wfv - 1);
    wxs[s] = xx - x0f;
  }
  __syncthreads();

  const int b = (int)ro[0];
  const unsigned short* xb = x_bf + (size_t)b * HWC * FPv;
  const int f2 = tid * 2;

  float acc[7][2] = {};
#pragma unroll
  for (int sy = 0; sy < 2; ++sy) {
    const int ry0 = ys0[sy] * Wfv;
    const int ry1 = ys1[sy] * Wfv;
    const float wy = wys[sy];
    const float cy = 1.f - wy;
#pragma unroll
    for (int pwsx = 0; pwsx < 14; ++pwsx) {
      const int xi0 = xs0[pwsx], xi1 = xs1[pwsx];
      const float wx = wxs[pwsx];
      const float cx = 1.f - wx;
      const unsigned u00 = *(const unsigned*)(xb + (size_t)(ry0 + xi0) * FPv + f2);
      const unsigned u01 = *(const unsigned*)(xb + (size_t)(ry0 + xi1) * FPv + f2);
      const unsigned u10 = *(const unsigned*)(xb + (size_t)(ry1 + xi0) * FPv + f2);
      const unsigned u11 = *(const unsigned*)(xb + (size_t)(ry1 + xi1) * FPv + f2);
      const float w00 = cy * cx, w01 = cy * wx, w10 = wy * cx, w11 = wy * wx;
      const int pw = pwsx >> 1;
      acc[pw][0] += w00 * bflo(u00) + w01 * bflo(u01) + w10 * bflo(u10) + w11 * bflo(u11);
      acc[pw][1] += w00 * bfhi(u00) + w01 * bfhi(u01) + w10 * bfhi(u10) + w11 * bfhi(u11);
    }
  }
  unsigned int* Prow = P_u + (size_t)r * (KTOT / 2);
#pragma unroll
  for (int pw = 0; pw < 7; ++pw) {
    const unsigned lo = f2bf(acc[pw][0] * 0.25f);
    const unsigned hi = f2bf(acc[pw][1] * 0.25f);
    Prow[(size_t)(ph * 7 + pw) * (FPv / 2) + tid] = lo | (hi << 16);
  }
}

// ---------------------------------------------------------------------------
// Kernel 3: MFMA GEMM, split-K by bin. partial[bin][r][c] = P[r]·Wt[c] (bin).
// ---------------------------------------------------------------------------
__global__ __launch_bounds__(256) void gemm2_kernel(
    const unsigned short* __restrict__ P, const unsigned short* __restrict__ Wt,
    float* __restrict__ partial) {
  const int tid = threadIdx.x;
  const int lane = tid & 63, wid = tid >> 6;
  const int rt = blockIdx.x;   // 0..7
  const int bin = blockIdx.y;  // 0..48
  const int arow = rt * 64 + wid * 16 + (lane & 15);
  const int kbase = bin * FPv + ((lane >> 4) << 3);
  const unsigned short* Ap = P + (size_t)arow * KTOT + kbase;
  const unsigned short* Bp = Wt + (size_t)(lane & 15) * KTOT + kbase;
  f32x4 acc[6] = {};
#pragma unroll 4
  for (int ks = 0; ks < 16; ++ks) {
    const bf16x8 a = *(const bf16x8*)(Ap + ks * 32);
#pragma unroll
    for (int n = 0; n < 6; ++n) {
      const bf16x8 bfr = *(const bf16x8*)(Bp + (size_t)n * 16 * KTOT + ks * 32);
      acc[n] = __builtin_amdgcn_mfma_f32_16x16x32_bf16(a, bfr, acc[n], 0, 0, 0);
    }
  }
  const int c_lo = lane & 15;
  const int rr = rt * 64 + wid * 16 + ((lane >> 4) << 2);
  float* pb = partial + (size_t)bin * PARTN;
#pragma unroll
  for (int n = 0; n < 6; ++n) {
    const int c = n * 16 + c_lo;
    if (c < NOUT) {
#pragma unroll
      for (int reg = 0; reg < 4; ++reg)
        pb[(size_t)(rr + reg) * NOUT + c] = acc[n][reg];
    }
  }
}

// ---------------------------------------------------------------------------
// Kernel 4: fixed-order reduction over 49 bins + bias -> final layout.
// ---------------------------------------------------------------------------
__global__ __launch_bounds__(256) void reduce_kernel(
    const float* __restrict__ partial, const float* __restrict__ bias_mean,
    float* __restrict__ out) {
  const int g = blockIdx.x * 256 + threadIdx.x;  // 0..43519
  const int r = g / NOUT;
  const int cc = g - r * NOUT;
  float s = 0.f;
  for (int b = 0; b < NBIN; ++b) s += partial[(size_t)b * PARTN + g];
  s = s * (1.0f / NBIN) + bias_mean[cc];
  if (cc < NCLSv)
    out[(size_t)r * NCLSv + cc] = s;
  else
    out[(size_t)RNUM * NCLSv + (size_t)r * 4 + (cc - NCLSv)] = s;
}

// ---------------------------------------------------------------------------
extern "C" void kernel_launch(void* const* d_in, const int* in_sizes, int n_in,
                              void* d_out, int out_size, void* d_ws,
                              size_t ws_size, hipStream_t stream) {
  const float* rois    = (const float*)d_in[0];
  const float* feat    = (const float*)d_in[1];
  const float* w_new   = (const float*)d_in[2];
  const float* w_score = (const float*)d_in[3];
  const float* b_score = (const float*)d_in[4];
  const float* w_bbox  = (const float*)d_in[5];
  const float* b_bbox  = (const float*)d_in[6];
  const void*  stridep = d_in[7];
  float* out = (float*)d_out;

  // ws layout (256B-aligned). featT (dead after gemm1) aliases partial.
  char* w = (char*)d_ws;
  unsigned short* x_bf = (unsigned short*)w;               // 4,358,144 B
  w += ((size_t)2 * HWC * FPv * 2 + 255) & ~(size_t)255;
  unsigned short* P = (unsigned short*)w;                  // 25,690,112 B
  w += ((size_t)RNUM * KTOT * 2 + 255) & ~(size_t)255;
  unsigned short* Wt = (unsigned short*)w;                 // 4,816,896 B
  w += ((size_t)96 * KTOT * 2 + 255) & ~(size_t)255;
  char* shared_blk = w;                                    // max(featT, partial)
  unsigned short* featT = (unsigned short*)shared_blk;     // 8,716,288 B
  float* partial = (float*)shared_blk;                     // 8,529,920 B
  w += ((size_t)2 * HWC * CINv * 2 + 255) & ~(size_t)255;
  unsigned short* wn_bf = (unsigned short*)w;              // 1,048,576 B
  w += ((size_t)FPv * CINv * 2 + 255) & ~(size_t)255;
  float* bias_mean = (float*)w;                            // 384 B

  {
    dim3 grid(96, 25);
    prepack_kernel<<<grid, 256, 0, stream>>>(w_score, b_score, w_bbox, b_bbox,
                                             Wt, bias_mean);
  }
  {
    convw_kernel<<<(FPv * CINv) / 1024, 256, 0, stream>>>(w_new, wn_bf);
  }
  {
    dim3 grid((HWC + 31) / 32, CINv / 32, 2);
    transpose_kernel<<<grid, 256, 0, stream>>>(feat, featT);
  }
  {
    dim3 grid((HWC + 63) / 64, FPv / 64, 2);
    gemm1_mfma_kernel<<<grid, 256, 0, stream>>>(featT, wn_bf, x_bf);
  }
  {
    dim3 grid(RNUM, 7);
    pool_kernel<<<grid, 256, 0, stream>>>(x_bf, rois, stridep,
                                          (unsigned int*)P);
  }
  {
    dim3 grid(RNUM / 64, NBIN);
    gemm2_kernel<<<grid, 256, 0, stream>>>(P, Wt, partial);
  }
  {
    reduce_kernel<<<(RNUM * NOUT) / 256, 256, 0, stream>>>(partial, bias_mean,
                                                           out);
  }
}

// Round 7
// 100.107 us; speedup vs baseline: 6.3867x; 1.0745x over previous
//
#include <hip/hip_runtime.h>
#include <hip/hip_bf16.h>

#define HWC   2128      // H*W = 38*56
#define Hf    38
#define Wfv   56
#define CINv  1024
#define FPv   512       // FEAT_PLANES
#define RNUM  512
#define NCLSv 81
#define NOUT  85        // 81 cls + 4 loc
#define NBIN  49
#define KTOT  (NBIN * FPv)            // 25088
#define PARTN ((size_t)RNUM * NOUT)   // 43520

typedef short bf16x8 __attribute__((ext_vector_type(8)));
typedef float f32x4 __attribute__((ext_vector_type(4)));

static __device__ __forceinline__ unsigned short f2bf(float f) {
  __hip_bfloat16 h = __float2bfloat16(f);
  return *reinterpret_cast<unsigned short*>(&h);
}
static __device__ __forceinline__ float bflo(unsigned u) {
  return __uint_as_float((u & 0xffffu) << 16);
}
static __device__ __forceinline__ float bfhi(unsigned u) {
  return __uint_as_float(u & 0xffff0000u);
}

// ---------------------------------------------------------------------------
// Kernel 0: prepack Wt[96][25088] bf16 + bias_mean[96]  AND  w_new -> bf16.
// Linear grid: blocks [0,2400) do Wt (c = bid%96, by = bid/96);
// blocks [2400,2912) convert w_new.
// ---------------------------------------------------------------------------
__global__ __launch_bounds__(256) void prep_kernel(
    const float* __restrict__ w_score, const float* __restrict__ b_score,
    const float* __restrict__ w_bbox, const float* __restrict__ b_bbox,
    const float* __restrict__ w_new, unsigned short* __restrict__ Wt,
    float* __restrict__ bias_mean, unsigned short* __restrict__ wn_bf) {
  const int bid = blockIdx.x;
  const int tid = threadIdx.x;
  if (bid >= 2400) {
    const int i = ((bid - 2400) * 256 + tid) * 4;  // < 512*1024
    const float4 v = *(const float4*)(w_new + i);
    ushort4 o;
    o.x = f2bf(v.x); o.y = f2bf(v.y); o.z = f2bf(v.z); o.w = f2bf(v.w);
    *(ushort4*)(wn_bf + i) = o;
    return;
  }
  const int c = bid % 96;
  const int by = bid / 96;  // 0..24
  if (by == 0 && tid == 0) {
    float s = 0.f;
    if (c < NCLSv)
      for (int b = 0; b < NBIN; ++b) s += b_score[c * NBIN + b];
    else if (c < NOUT)
      for (int b = 0; b < NBIN; ++b) s += b_bbox[(c - NCLSv) * NBIN + b];
    bias_mean[c] = s * (1.0f / NBIN);
  }
  const int k0 = by * 1024 + tid * 4;
  if (k0 >= KTOT) return;
  const int bin = k0 >> 9, f = k0 & 511;
  float4 v = make_float4(0.f, 0.f, 0.f, 0.f);
  if (c < NCLSv)
    v = *(const float4*)(w_score + ((size_t)(c * NBIN + bin)) * FPv + f);
  else if (c < NOUT)
    v = *(const float4*)(w_bbox + ((size_t)((c - NCLSv) * NBIN + bin)) * FPv + f);
  ushort4 o;
  o.x = f2bf(v.x); o.y = f2bf(v.y); o.z = f2bf(v.z); o.w = f2bf(v.w);
  *(ushort4*)(Wt + (size_t)c * KTOT + k0) = o;
}

// ---------------------------------------------------------------------------
// Kernel 0c: transpose+convert feat [b][c][hw] fp32 -> featT [b][hw][c] bf16.
// ---------------------------------------------------------------------------
__global__ __launch_bounds__(256) void transpose_kernel(
    const float* __restrict__ feat, unsigned short* __restrict__ featT) {
  __shared__ float t[32][33];
  const int b = blockIdx.z;
  const int hw0 = blockIdx.x * 32, c0 = blockIdx.y * 32;
  const int tx = threadIdx.x & 31, ty = threadIdx.x >> 5;  // 32 x 8
  const float* fb = feat + (size_t)b * CINv * HWC;
  const int hw = hw0 + tx;
#pragma unroll
  for (int i = 0; i < 4; ++i) {
    const int c = c0 + ty * 4 + i;
    t[ty * 4 + i][tx] = (hw < HWC) ? fb[(size_t)c * HWC + hw] : 0.f;
  }
  __syncthreads();
  unsigned short* ft = featT + (size_t)b * HWC * CINv;
#pragma unroll
  for (int i = 0; i < 4; ++i) {
    const int hwo = hw0 + ty * 4 + i;
    if (hwo < HWC) ft[(size_t)hwo * CINv + c0 + tx] = f2bf(t[tx][ty * 4 + i]);
  }
}

// ---------------------------------------------------------------------------
// Kernel 1: MFMA GEMM: x_bf[b][hw][f] = sum_c featT[b][hw][c] * wn_bf[f][c].
// K-chunk 128; B tile staged in LDS (issue-early/write-late dbuf);
// A fragments prefetched one chunk ahead in registers.
// ---------------------------------------------------------------------------
#define BSTRIDE 136  // 128 + 8 pad (elems)
__global__ __launch_bounds__(256) void gemm1_mfma_kernel(
    const unsigned short* __restrict__ featT,
    const unsigned short* __restrict__ wn_bf,
    unsigned short* __restrict__ x_bf) {
  __shared__ unsigned short Bs[64 * BSTRIDE];
  const int tid = threadIdx.x;
  const int lane = tid & 63, wid = tid >> 6;
  const int b = blockIdx.z;
  const int f0 = blockIdx.y * 64;
  const int hwbase = blockIdx.x * 64 + wid * 16;
  const int arow = min(hwbase + (lane & 15), HWC - 1);
  const int fr_f = lane & 15;
  const int fr_k = (lane >> 4) << 3;
  const unsigned short* Ap = featT + ((size_t)b * HWC + arow) * CINv + fr_k;
  const int sr = tid >> 2;
  const int sc = (tid & 3) * 8;
  const unsigned short* Bg = wn_bf + (size_t)(f0 + sr) * CINv + sc;

  uint4 breg[4];
  bf16x8 aCur[4], aNxt[4];
#pragma unroll
  for (int i = 0; i < 4; ++i) breg[i] = *(const uint4*)(Bg + i * 32);
#pragma unroll
  for (int s = 0; s < 4; ++s) aCur[s] = *(const bf16x8*)(Ap + s * 32);

  f32x4 acc[4] = {};
  for (int kc = 0; kc < CINv; kc += 128) {
    __syncthreads();
#pragma unroll
    for (int i = 0; i < 4; ++i)
      *(uint4*)&Bs[sr * BSTRIDE + sc + i * 32] = breg[i];
    const int kn = kc + 128;
    if (kn < CINv) {
#pragma unroll
      for (int i = 0; i < 4; ++i) breg[i] = *(const uint4*)(Bg + kn + i * 32);
#pragma unroll
      for (int s = 0; s < 4; ++s) aNxt[s] = *(const bf16x8*)(Ap + kn + s * 32);
    }
    __syncthreads();
#pragma unroll
    for (int s = 0; s < 4; ++s) {
#pragma unroll
      for (int n = 0; n < 4; ++n) {
        const bf16x8 bv =
            *(const bf16x8*)&Bs[(fr_f + n * 16) * BSTRIDE + s * 32 + fr_k];
        acc[n] =
            __builtin_amdgcn_mfma_f32_16x16x32_bf16(aCur[s], bv, acc[n], 0, 0, 0);
      }
    }
#pragma unroll
    for (int s = 0; s < 4; ++s) aCur[s] = aNxt[s];
  }
  const int c_lo = lane & 15;
  const int rbase = hwbase + ((lane >> 4) << 2);
#pragma unroll
  for (int n = 0; n < 4; ++n) {
#pragma unroll
    for (int reg = 0; reg < 4; ++reg) {
      const int hwo = rbase + reg;
      if (hwo < HWC)
        x_bf[((size_t)b * HWC + hwo) * FPv + f0 + n * 16 + c_lo] =
            f2bf(acc[n][reg]);
    }
  }
}

// ---------------------------------------------------------------------------
// Kernel 2: PSRoI pooling -> P[r][bin*512+f] (bf16 pairs). Grid (512, 7).
// ---------------------------------------------------------------------------
__global__ __launch_bounds__(256) void pool_kernel(
    const unsigned short* __restrict__ x_bf, const float* __restrict__ rois,
    const void* __restrict__ stride_ptr, unsigned int* __restrict__ P_u) {
  __shared__ int ys0[2], ys1[2];
  __shared__ float wys[2];
  __shared__ int xs0[14], xs1[14];
  __shared__ float wxs[14];
  const int tid = threadIdx.x;
  const int r = blockIdx.x;
  const int ph = blockIdx.y;  // 0..6
  const float* ro = rois + (size_t)r * 5;

  float stride_f;
  {
    const int iv = ((const int*)stride_ptr)[0];
    if (iv >= 1 && iv <= 4096) stride_f = (float)iv;
    else stride_f = ((const float*)stride_ptr)[0];
  }
  const float inv = 1.0f / stride_f;

  if (tid < 2) {
    const float y1v = ro[2] * inv, y2v = ro[4] * inv;
    const float bhf = fmaxf(y2v - y1v, 0.1f) * (1.0f / 7.0f);
    const int sy = tid;
    float yy = y1v + ((float)ph + ((float)sy + 0.5f) * 0.5f) * bhf;
    yy = fminf(fmaxf(yy, 0.f), (float)(Hf - 1));
    const float y0f = floorf(yy);
    ys0[tid] = (int)y0f;
    ys1[tid] = min((int)y0f + 1, Hf - 1);
    wys[tid] = yy - y0f;
  } else if (tid >= 64 && tid < 78) {
    const int s = tid - 64;
    const float x1v = ro[1] * inv, x2v = ro[3] * inv;
    const float bwf = fmaxf(x2v - x1v, 0.1f) * (1.0f / 7.0f);
    const int pw = s >> 1, sx = s & 1;
    float xx = x1v + ((float)pw + ((float)sx + 0.5f) * 0.5f) * bwf;
    xx = fminf(fmaxf(xx, 0.f), (float)(Wfv - 1));
    const float x0f = floorf(xx);
    xs0[s] = (int)x0f;
    xs1[s] = min((int)x0f + 1, Wfv - 1);
    wxs[s] = xx - x0f;
  }
  __syncthreads();

  const int b = (int)ro[0];
  const unsigned short* xb = x_bf + (size_t)b * HWC * FPv;
  const int f2 = tid * 2;

  float acc[7][2] = {};
#pragma unroll
  for (int sy = 0; sy < 2; ++sy) {
    const int ry0 = ys0[sy] * Wfv;
    const int ry1 = ys1[sy] * Wfv;
    const float wy = wys[sy];
    const float cy = 1.f - wy;
#pragma unroll
    for (int pwsx = 0; pwsx < 14; ++pwsx) {
      const int xi0 = xs0[pwsx], xi1 = xs1[pwsx];
      const float wx = wxs[pwsx];
      const float cx = 1.f - wx;
      const unsigned u00 = *(const unsigned*)(xb + (size_t)(ry0 + xi0) * FPv + f2);
      const unsigned u01 = *(const unsigned*)(xb + (size_t)(ry0 + xi1) * FPv + f2);
      const unsigned u10 = *(const unsigned*)(xb + (size_t)(ry1 + xi0) * FPv + f2);
      const unsigned u11 = *(const unsigned*)(xb + (size_t)(ry1 + xi1) * FPv + f2);
      const float w00 = cy * cx, w01 = cy * wx, w10 = wy * cx, w11 = wy * wx;
      const int pw = pwsx >> 1;
      acc[pw][0] += w00 * bflo(u00) + w01 * bflo(u01) + w10 * bflo(u10) + w11 * bflo(u11);
      acc[pw][1] += w00 * bfhi(u00) + w01 * bfhi(u01) + w10 * bfhi(u10) + w11 * bfhi(u11);
    }
  }
  unsigned int* Prow = P_u + (size_t)r * (KTOT / 2);
#pragma unroll
  for (int pw = 0; pw < 7; ++pw) {
    const unsigned lo = f2bf(acc[pw][0] * 0.25f);
    const unsigned hi = f2bf(acc[pw][1] * 0.25f);
    Prow[(size_t)(ph * 7 + pw) * (FPv / 2) + tid] = lo | (hi << 16);
  }
}

// ---------------------------------------------------------------------------
// Kernel 3: MFMA GEMM v2, split-K by bin: partial[bin][r][c] = P[r]·Wt[c].
// B tile (96 x 128, 26KB LDS) staged w/ reg dbuf; A prefetched in regs.
// Grid (8 roi-tiles of 64, 49 bins), 256 threads = 4 waves.
// ---------------------------------------------------------------------------
#define B2STRIDE 136
__global__ __launch_bounds__(256) void gemm2_kernel(
    const unsigned short* __restrict__ P, const unsigned short* __restrict__ Wt,
    float* __restrict__ partial) {
  __shared__ unsigned short Bs[96 * B2STRIDE];
  const int tid = threadIdx.x;
  const int lane = tid & 63, wid = tid >> 6;
  const int rt = blockIdx.x;   // 0..7
  const int bin = blockIdx.y;  // 0..48
  const int arow = rt * 64 + wid * 16 + (lane & 15);
  const int fr_f = lane & 15;
  const int fr_k = (lane >> 4) << 3;
  const unsigned short* Ap = P + (size_t)arow * KTOT + bin * FPv + fr_k;
  // staging map: thread covers linear elems [t*48, t*48+48) of 96x128 tile
  int srow[3], scol[3];
#pragma unroll
  for (int g = 0; g < 3; ++g) {
    const int idx = tid * 48 + g * 16;
    srow[g] = idx >> 7;
    scol[g] = idx & 127;
  }
  const unsigned short* WtB = Wt + (size_t)bin * FPv;

  uint4 breg[6];
  bf16x8 aCur[4], aNxt[4];
#pragma unroll
  for (int g = 0; g < 3; ++g) {
    const unsigned short* src = WtB + (size_t)srow[g] * KTOT + scol[g];
    breg[g * 2] = *(const uint4*)src;
    breg[g * 2 + 1] = *(const uint4*)(src + 8);
  }
#pragma unroll
  for (int s = 0; s < 4; ++s) aCur[s] = *(const bf16x8*)(Ap + s * 32);

  f32x4 acc[6] = {};
  for (int kc = 0; kc < FPv; kc += 128) {
    __syncthreads();
#pragma unroll
    for (int g = 0; g < 3; ++g) {
      unsigned short* dst = &Bs[srow[g] * B2STRIDE + scol[g]];
      *(uint4*)dst = breg[g * 2];
      *(uint4*)(dst + 8) = breg[g * 2 + 1];
    }
    const int kn = kc + 128;
    if (kn < FPv) {
#pragma unroll
      for (int g = 0; g < 3; ++g) {
        const unsigned short* src = WtB + (size_t)srow[g] * KTOT + kn + scol[g];
        breg[g * 2] = *(const uint4*)src;
        breg[g * 2 + 1] = *(const uint4*)(src + 8);
      }
#pragma unroll
      for (int s = 0; s < 4; ++s) aNxt[s] = *(const bf16x8*)(Ap + kn + s * 32);
    }
    __syncthreads();
#pragma unroll
    for (int s = 0; s < 4; ++s) {
#pragma unroll
      for (int n = 0; n < 6; ++n) {
        const bf16x8 bv =
            *(const bf16x8*)&Bs[(fr_f + n * 16) * B2STRIDE + s * 32 + fr_k];
        acc[n] =
            __builtin_amdgcn_mfma_f32_16x16x32_bf16(aCur[s], bv, acc[n], 0, 0, 0);
      }
    }
#pragma unroll
    for (int s = 0; s < 4; ++s) aCur[s] = aNxt[s];
  }
  const int c_lo = lane & 15;
  const int rr = rt * 64 + wid * 16 + ((lane >> 4) << 2);
  float* pb = partial + (size_t)bin * PARTN;
#pragma unroll
  for (int n = 0; n < 6; ++n) {
    const int c = n * 16 + c_lo;
    if (c < NOUT) {
#pragma unroll
      for (int reg = 0; reg < 4; ++reg)
        pb[(size_t)(rr + reg) * NOUT + c] = acc[n][reg];
    }
  }
}

// ---------------------------------------------------------------------------
// Kernel 4: fixed-order reduction over 49 bins + bias -> final layout.
// ---------------------------------------------------------------------------
__global__ __launch_bounds__(256) void reduce_kernel(
    const float* __restrict__ partial, const float* __restrict__ bias_mean,
    float* __restrict__ out) {
  const int g = blockIdx.x * 256 + threadIdx.x;  // 0..43519
  const int r = g / NOUT;
  const int cc = g - r * NOUT;
  float s = 0.f;
  for (int b = 0; b < NBIN; ++b) s += partial[(size_t)b * PARTN + g];
  s = s * (1.0f / NBIN) + bias_mean[cc];
  if (cc < NCLSv)
    out[(size_t)r * NCLSv + cc] = s;
  else
    out[(size_t)RNUM * NCLSv + (size_t)r * 4 + (cc - NCLSv)] = s;
}

// ---------------------------------------------------------------------------
extern "C" void kernel_launch(void* const* d_in, const int* in_sizes, int n_in,
                              void* d_out, int out_size, void* d_ws,
                              size_t ws_size, hipStream_t stream) {
  const float* rois    = (const float*)d_in[0];
  const float* feat    = (const float*)d_in[1];
  const float* w_new   = (const float*)d_in[2];
  const float* w_score = (const float*)d_in[3];
  const float* b_score = (const float*)d_in[4];
  const float* w_bbox  = (const float*)d_in[5];
  const float* b_bbox  = (const float*)d_in[6];
  const void*  stridep = d_in[7];
  float* out = (float*)d_out;

  // ws layout (256B-aligned). featT (dead after gemm1) aliases partial.
  char* w = (char*)d_ws;
  unsigned short* x_bf = (unsigned short*)w;               // 4,358,144 B
  w += ((size_t)2 * HWC * FPv * 2 + 255) & ~(size_t)255;
  unsigned short* P = (unsigned short*)w;                  // 25,690,112 B
  w += ((size_t)RNUM * KTOT * 2 + 255) & ~(size_t)255;
  unsigned short* Wt = (unsigned short*)w;                 // 4,816,896 B
  w += ((size_t)96 * KTOT * 2 + 255) & ~(size_t)255;
  char* shared_blk = w;                                    // max(featT, partial)
  unsigned short* featT = (unsigned short*)shared_blk;     // 8,716,288 B
  float* partial = (float*)shared_blk;                     // 8,529,920 B
  w += ((size_t)2 * HWC * CINv * 2 + 255) & ~(size_t)255;
  unsigned short* wn_bf = (unsigned short*)w;              // 1,048,576 B
  w += ((size_t)FPv * CINv * 2 + 255) & ~(size_t)255;
  float* bias_mean = (float*)w;                            // 384 B

  {
    prep_kernel<<<2912, 256, 0, stream>>>(w_score, b_score, w_bbox, b_bbox,
                                          w_new, Wt, bias_mean, wn_bf);
  }
  {
    dim3 grid((HWC + 31) / 32, CINv / 32, 2);
    transpose_kernel<<<grid, 256, 0, stream>>>(feat, featT);
  }
  {
    dim3 grid((HWC + 63) / 64, FPv / 64, 2);
    gemm1_mfma_kernel<<<grid, 256, 0, stream>>>(featT, wn_bf, x_bf);
  }
  {
    dim3 grid(RNUM, 7);
    pool_kernel<<<grid, 256, 0, stream>>>(x_bf, rois, stridep,
                                          (unsigned int*)P);
  }
  {
    dim3 grid(RNUM / 64, NBIN);
    gemm2_kernel<<<grid, 256, 0, stream>>>(P, Wt, partial);
  }
  {
    reduce_kernel<<<(RNUM * NOUT) / 256, 256, 0, stream>>>(partial, bias_mean,
                                                           out);
  }
}

// Round 8
// 99.320 us; speedup vs baseline: 6.4374x; 1.0079x over previous
//
#include <hip/hip_runtime.h>
#include <hip/hip_bf16.h>

#define HWC   2128      // H*W = 38*56
#define Hf    38
#define Wfv   56
#define CINv  1024
#define FPv   512       // FEAT_PLANES
#define RNUM  512
#define NCLSv 81
#define NOUT  85        // 81 cls + 4 loc
#define NBIN  49
#define KTOT  (NBIN * FPv)            // 25088
#define PARTN ((size_t)RNUM * NOUT)   // 43520

typedef short bf16x8 __attribute__((ext_vector_type(8)));
typedef float f32x4 __attribute__((ext_vector_type(4)));

static __device__ __forceinline__ unsigned short f2bf(float f) {
  __hip_bfloat16 h = __float2bfloat16(f);
  return *reinterpret_cast<unsigned short*>(&h);
}
static __device__ __forceinline__ float bflo(unsigned u) {
  return __uint_as_float((u & 0xffffu) << 16);
}
static __device__ __forceinline__ float bfhi(unsigned u) {
  return __uint_as_float(u & 0xffff0000u);
}

// ---------------------------------------------------------------------------
// Kernel 0 (fused prep): linear grid of 7200 blocks.
//   [0,2400):    Wt[96][25088] bf16 prepack + bias_mean[96]
//   [2400,2912): w_new fp32 -> bf16
//   [2912,7200): feat [b][c][hw] fp32 -> featT [b][hw][c] bf16 (32x32 tiles)
// ---------------------------------------------------------------------------
__global__ __launch_bounds__(256) void prep_kernel(
    const float* __restrict__ w_score, const float* __restrict__ b_score,
    const float* __restrict__ w_bbox, const float* __restrict__ b_bbox,
    const float* __restrict__ w_new, const float* __restrict__ feat,
    unsigned short* __restrict__ Wt, float* __restrict__ bias_mean,
    unsigned short* __restrict__ wn_bf, unsigned short* __restrict__ featT) {
  __shared__ float t[32][33];
  const int bid = blockIdx.x;
  const int tid = threadIdx.x;
  if (bid >= 2912) {
    // ---- transpose+convert feat ----
    const int tb = bid - 2912;        // 0..4287
    const int bz = tb / 2144;         // batch
    const int rem = tb - bz * 2144;   // 67 x 32 tiles
    const int hw0 = (rem % 67) * 32;
    const int c0 = (rem / 67) * 32;
    const int tx = tid & 31, ty = tid >> 5;  // 32 x 8
    const float* fb = feat + (size_t)bz * CINv * HWC;
    const int hw = hw0 + tx;
#pragma unroll
    for (int i = 0; i < 4; ++i) {
      const int c = c0 + ty * 4 + i;
      t[ty * 4 + i][tx] = (hw < HWC) ? fb[(size_t)c * HWC + hw] : 0.f;
    }
    __syncthreads();
    unsigned short* ft = featT + (size_t)bz * HWC * CINv;
#pragma unroll
    for (int i = 0; i < 4; ++i) {
      const int hwo = hw0 + ty * 4 + i;
      if (hwo < HWC) ft[(size_t)hwo * CINv + c0 + tx] = f2bf(t[tx][ty * 4 + i]);
    }
    return;
  }
  if (bid >= 2400) {
    const int i = ((bid - 2400) * 256 + tid) * 4;  // < 512*1024
    const float4 v = *(const float4*)(w_new + i);
    ushort4 o;
    o.x = f2bf(v.x); o.y = f2bf(v.y); o.z = f2bf(v.z); o.w = f2bf(v.w);
    *(ushort4*)(wn_bf + i) = o;
    return;
  }
  const int c = bid % 96;
  const int by = bid / 96;  // 0..24
  if (by == 0 && tid == 0) {
    float s = 0.f;
    if (c < NCLSv)
      for (int b = 0; b < NBIN; ++b) s += b_score[c * NBIN + b];
    else if (c < NOUT)
      for (int b = 0; b < NBIN; ++b) s += b_bbox[(c - NCLSv) * NBIN + b];
    bias_mean[c] = s * (1.0f / NBIN);
  }
  const int k0 = by * 1024 + tid * 4;
  if (k0 >= KTOT) return;
  const int bin = k0 >> 9, f = k0 & 511;
  float4 v = make_float4(0.f, 0.f, 0.f, 0.f);
  if (c < NCLSv)
    v = *(const float4*)(w_score + ((size_t)(c * NBIN + bin)) * FPv + f);
  else if (c < NOUT)
    v = *(const float4*)(w_bbox + ((size_t)((c - NCLSv) * NBIN + bin)) * FPv + f);
  ushort4 o;
  o.x = f2bf(v.x); o.y = f2bf(v.y); o.z = f2bf(v.z); o.w = f2bf(v.w);
  *(ushort4*)(Wt + (size_t)c * KTOT + k0) = o;
}

// ---------------------------------------------------------------------------
// Kernel 1: MFMA GEMM v3: x_bf[b][hw][f] = sum_c featT[b][hw][c]*wn_bf[f][c].
// Per-wave tile 16hw x 32f (was 16x64) -> 2x the waves (4.25/SIMD) for
// latency hiding. Block = 4 waves = 64hw x 32f; BK=128; B tile in LDS with
// issue-early/write-late reg dbuf; A prefetched one chunk ahead in regs.
// ---------------------------------------------------------------------------
#define BSTRIDE1 136
__global__ __launch_bounds__(256) void gemm1_mfma_kernel(
    const unsigned short* __restrict__ featT,
    const unsigned short* __restrict__ wn_bf,
    unsigned short* __restrict__ x_bf) {
  __shared__ unsigned short Bs[32 * BSTRIDE1];  // 8.7 KB
  const int tid = threadIdx.x;
  const int lane = tid & 63, wid = tid >> 6;
  const int b = blockIdx.z;
  const int f0 = blockIdx.y * 32;
  const int hwbase = blockIdx.x * 64 + wid * 16;
  const int arow = min(hwbase + (lane & 15), HWC - 1);
  const int fr_f = lane & 15;
  const int fr_k = (lane >> 4) << 3;
  const unsigned short* Ap = featT + ((size_t)b * HWC + arow) * CINv + fr_k;
  // B staging: thread t -> row t>>3 (0..31), cols (t&7)*16 .. +15
  const int sr = tid >> 3;
  const int sc = (tid & 7) * 16;
  const unsigned short* Bg = wn_bf + (size_t)(f0 + sr) * CINv + sc;

  uint4 breg[2];
  bf16x8 aCur[4], aNxt[4];
  breg[0] = *(const uint4*)(Bg);
  breg[1] = *(const uint4*)(Bg + 8);
#pragma unroll
  for (int s = 0; s < 4; ++s) aCur[s] = *(const bf16x8*)(Ap + s * 32);

  f32x4 acc[2] = {};
  for (int kc = 0; kc < CINv; kc += 128) {
    __syncthreads();
    *(uint4*)&Bs[sr * BSTRIDE1 + sc] = breg[0];
    *(uint4*)&Bs[sr * BSTRIDE1 + sc + 8] = breg[1];
    const int kn = kc + 128;
    if (kn < CINv) {
      breg[0] = *(const uint4*)(Bg + kn);
      breg[1] = *(const uint4*)(Bg + kn + 8);
#pragma unroll
      for (int s = 0; s < 4; ++s) aNxt[s] = *(const bf16x8*)(Ap + kn + s * 32);
    }
    __syncthreads();
#pragma unroll
    for (int s = 0; s < 4; ++s) {
#pragma unroll
      for (int n = 0; n < 2; ++n) {
        const bf16x8 bv =
            *(const bf16x8*)&Bs[(fr_f + n * 16) * BSTRIDE1 + s * 32 + fr_k];
        acc[n] =
            __builtin_amdgcn_mfma_f32_16x16x32_bf16(aCur[s], bv, acc[n], 0, 0, 0);
      }
    }
#pragma unroll
    for (int s = 0; s < 4; ++s) aCur[s] = aNxt[s];
  }
  // D: col = lane&15 (f), row = (lane>>4)*4 + reg (hw)
  const int c_lo = lane & 15;
  const int rbase = hwbase + ((lane >> 4) << 2);
#pragma unroll
  for (int n = 0; n < 2; ++n) {
#pragma unroll
    for (int reg = 0; reg < 4; ++reg) {
      const int hwo = rbase + reg;
      if (hwo < HWC)
        x_bf[((size_t)b * HWC + hwo) * FPv + f0 + n * 16 + c_lo] =
            f2bf(acc[n][reg]);
    }
  }
}

// ---------------------------------------------------------------------------
// Kernel 2: PSRoI pooling -> P[r][bin*512+f] (bf16 pairs). Grid (512, 7).
// ---------------------------------------------------------------------------
__global__ __launch_bounds__(256) void pool_kernel(
    const unsigned short* __restrict__ x_bf, const float* __restrict__ rois,
    const void* __restrict__ stride_ptr, unsigned int* __restrict__ P_u) {
  __shared__ int ys0[2], ys1[2];
  __shared__ float wys[2];
  __shared__ int xs0[14], xs1[14];
  __shared__ float wxs[14];
  const int tid = threadIdx.x;
  const int r = blockIdx.x;
  const int ph = blockIdx.y;  // 0..6
  const float* ro = rois + (size_t)r * 5;

  float stride_f;
  {
    const int iv = ((const int*)stride_ptr)[0];
    if (iv >= 1 && iv <= 4096) stride_f = (float)iv;
    else stride_f = ((const float*)stride_ptr)[0];
  }
  const float inv = 1.0f / stride_f;

  if (tid < 2) {
    const float y1v = ro[2] * inv, y2v = ro[4] * inv;
    const float bhf = fmaxf(y2v - y1v, 0.1f) * (1.0f / 7.0f);
    const int sy = tid;
    float yy = y1v + ((float)ph + ((float)sy + 0.5f) * 0.5f) * bhf;
    yy = fminf(fmaxf(yy, 0.f), (float)(Hf - 1));
    const float y0f = floorf(yy);
    ys0[tid] = (int)y0f;
    ys1[tid] = min((int)y0f + 1, Hf - 1);
    wys[tid] = yy - y0f;
  } else if (tid >= 64 && tid < 78) {
    const int s = tid - 64;
    const float x1v = ro[1] * inv, x2v = ro[3] * inv;
    const float bwf = fmaxf(x2v - x1v, 0.1f) * (1.0f / 7.0f);
    const int pw = s >> 1, sx = s & 1;
    float xx = x1v + ((float)pw + ((float)sx + 0.5f) * 0.5f) * bwf;
    xx = fminf(fmaxf(xx, 0.f), (float)(Wfv - 1));
    const float x0f = floorf(xx);
    xs0[s] = (int)x0f;
    xs1[s] = min((int)x0f + 1, Wfv - 1);
    wxs[s] = xx - x0f;
  }
  __syncthreads();

  const int b = (int)ro[0];
  const unsigned short* xb = x_bf + (size_t)b * HWC * FPv;
  const int f2 = tid * 2;

  float acc[7][2] = {};
#pragma unroll
  for (int sy = 0; sy < 2; ++sy) {
    const int ry0 = ys0[sy] * Wfv;
    const int ry1 = ys1[sy] * Wfv;
    const float wy = wys[sy];
    const float cy = 1.f - wy;
#pragma unroll
    for (int pwsx = 0; pwsx < 14; ++pwsx) {
      const int xi0 = xs0[pwsx], xi1 = xs1[pwsx];
      const float wx = wxs[pwsx];
      const float cx = 1.f - wx;
      const unsigned u00 = *(const unsigned*)(xb + (size_t)(ry0 + xi0) * FPv + f2);
      const unsigned u01 = *(const unsigned*)(xb + (size_t)(ry0 + xi1) * FPv + f2);
      const unsigned u10 = *(const unsigned*)(xb + (size_t)(ry1 + xi0) * FPv + f2);
      const unsigned u11 = *(const unsigned*)(xb + (size_t)(ry1 + xi1) * FPv + f2);
      const float w00 = cy * cx, w01 = cy * wx, w10 = wy * cx, w11 = wy * wx;
      const int pw = pwsx >> 1;
      acc[pw][0] += w00 * bflo(u00) + w01 * bflo(u01) + w10 * bflo(u10) + w11 * bflo(u11);
      acc[pw][1] += w00 * bfhi(u00) + w01 * bfhi(u01) + w10 * bfhi(u10) + w11 * bfhi(u11);
    }
  }
  unsigned int* Prow = P_u + (size_t)r * (KTOT / 2);
#pragma unroll
  for (int pw = 0; pw < 7; ++pw) {
    const unsigned lo = f2bf(acc[pw][0] * 0.25f);
    const unsigned hi = f2bf(acc[pw][1] * 0.25f);
    Prow[(size_t)(ph * 7 + pw) * (FPv / 2) + tid] = lo | (hi << 16);
  }
}

// ---------------------------------------------------------------------------
// Kernel 3: MFMA GEMM v2, split-K by bin: partial[bin][r][c] = P[r]·Wt[c].
// ---------------------------------------------------------------------------
#define B2STRIDE 136
__global__ __launch_bounds__(256) void gemm2_kernel(
    const unsigned short* __restrict__ P, const unsigned short* __restrict__ Wt,
    float* __restrict__ partial) {
  __shared__ unsigned short Bs[96 * B2STRIDE];
  const int tid = threadIdx.x;
  const int lane = tid & 63, wid = tid >> 6;
  const int rt = blockIdx.x;   // 0..7
  const int bin = blockIdx.y;  // 0..48
  const int arow = rt * 64 + wid * 16 + (lane & 15);
  const int fr_f = lane & 15;
  const int fr_k = (lane >> 4) << 3;
  const unsigned short* Ap = P + (size_t)arow * KTOT + bin * FPv + fr_k;
  int srow[3], scol[3];
#pragma unroll
  for (int g = 0; g < 3; ++g) {
    const int idx = tid * 48 + g * 16;
    srow[g] = idx >> 7;
    scol[g] = idx & 127;
  }
  const unsigned short* WtB = Wt + (size_t)bin * FPv;

  uint4 breg[6];
  bf16x8 aCur[4], aNxt[4];
#pragma unroll
  for (int g = 0; g < 3; ++g) {
    const unsigned short* src = WtB + (size_t)srow[g] * KTOT + scol[g];
    breg[g * 2] = *(const uint4*)src;
    breg[g * 2 + 1] = *(const uint4*)(src + 8);
  }
#pragma unroll
  for (int s = 0; s < 4; ++s) aCur[s] = *(const bf16x8*)(Ap + s * 32);

  f32x4 acc[6] = {};
  for (int kc = 0; kc < FPv; kc += 128) {
    __syncthreads();
#pragma unroll
    for (int g = 0; g < 3; ++g) {
      unsigned short* dst = &Bs[srow[g] * B2STRIDE + scol[g]];
      *(uint4*)dst = breg[g * 2];
      *(uint4*)(dst + 8) = breg[g * 2 + 1];
    }
    const int kn = kc + 128;
    if (kn < FPv) {
#pragma unroll
      for (int g = 0; g < 3; ++g) {
        const unsigned short* src = WtB + (size_t)srow[g] * KTOT + kn + scol[g];
        breg[g * 2] = *(const uint4*)src;
        breg[g * 2 + 1] = *(const uint4*)(src + 8);
      }
#pragma unroll
      for (int s = 0; s < 4; ++s) aNxt[s] = *(const bf16x8*)(Ap + kn + s * 32);
    }
    __syncthreads();
#pragma unroll
    for (int s = 0; s < 4; ++s) {
#pragma unroll
      for (int n = 0; n < 6; ++n) {
        const bf16x8 bv =
            *(const bf16x8*)&Bs[(fr_f + n * 16) * B2STRIDE + s * 32 + fr_k];
        acc[n] =
            __builtin_amdgcn_mfma_f32_16x16x32_bf16(aCur[s], bv, acc[n], 0, 0, 0);
      }
    }
#pragma unroll
    for (int s = 0; s < 4; ++s) aCur[s] = aNxt[s];
  }
  const int c_lo = lane & 15;
  const int rr = rt * 64 + wid * 16 + ((lane >> 4) << 2);
  float* pb = partial + (size_t)bin * PARTN;
#pragma unroll
  for (int n = 0; n < 6; ++n) {
    const int c = n * 16 + c_lo;
    if (c < NOUT) {
#pragma unroll
      for (int reg = 0; reg < 4; ++reg)
        pb[(size_t)(rr + reg) * NOUT + c] = acc[n][reg];
    }
  }
}

// ---------------------------------------------------------------------------
// Kernel 4: fixed-order reduction over 49 bins + bias -> final layout.
// ---------------------------------------------------------------------------
__global__ __launch_bounds__(256) void reduce_kernel(
    const float* __restrict__ partial, const float* __restrict__ bias_mean,
    float* __restrict__ out) {
  const int g = blockIdx.x * 256 + threadIdx.x;  // 0..43519
  const int r = g / NOUT;
  const int cc = g - r * NOUT;
  float s = 0.f;
  for (int b = 0; b < NBIN; ++b) s += partial[(size_t)b * PARTN + g];
  s = s * (1.0f / NBIN) + bias_mean[cc];
  if (cc < NCLSv)
    out[(size_t)r * NCLSv + cc] = s;
  else
    out[(size_t)RNUM * NCLSv + (size_t)r * 4 + (cc - NCLSv)] = s;
}

// ---------------------------------------------------------------------------
extern "C" void kernel_launch(void* const* d_in, const int* in_sizes, int n_in,
                              void* d_out, int out_size, void* d_ws,
                              size_t ws_size, hipStream_t stream) {
  const float* rois    = (const float*)d_in[0];
  const float* feat    = (const float*)d_in[1];
  const float* w_new   = (const float*)d_in[2];
  const float* w_score = (const float*)d_in[3];
  const float* b_score = (const float*)d_in[4];
  const float* w_bbox  = (const float*)d_in[5];
  const float* b_bbox  = (const float*)d_in[6];
  const void*  stridep = d_in[7];
  float* out = (float*)d_out;

  // ws layout (256B-aligned). featT (dead after gemm1) aliases partial.
  char* w = (char*)d_ws;
  unsigned short* x_bf = (unsigned short*)w;               // 4,358,144 B
  w += ((size_t)2 * HWC * FPv * 2 + 255) & ~(size_t)255;
  unsigned short* P = (unsigned short*)w;                  // 25,690,112 B
  w += ((size_t)RNUM * KTOT * 2 + 255) & ~(size_t)255;
  unsigned short* Wt = (unsigned short*)w;                 // 4,816,896 B
  w += ((size_t)96 * KTOT * 2 + 255) & ~(size_t)255;
  char* shared_blk = w;                                    // max(featT, partial)
  unsigned short* featT = (unsigned short*)shared_blk;     // 8,716,288 B
  float* partial = (float*)shared_blk;                     // 8,529,920 B
  w += ((size_t)2 * HWC * CINv * 2 + 255) & ~(size_t)255;
  unsigned short* wn_bf = (unsigned short*)w;              // 1,048,576 B
  w += ((size_t)FPv * CINv * 2 + 255) & ~(size_t)255;
  float* bias_mean = (float*)w;                            // 384 B

  {
    prep_kernel<<<7200, 256, 0, stream>>>(w_score, b_score, w_bbox, b_bbox,
                                          w_new, feat, Wt, bias_mean, wn_bf,
                                          featT);
  }
  {
    dim3 grid((HWC + 63) / 64, FPv / 32, 2);
    gemm1_mfma_kernel<<<grid, 256, 0, stream>>>(featT, wn_bf, x_bf);
  }
  {
    dim3 grid(RNUM, 7);
    pool_kernel<<<grid, 256, 0, stream>>>(x_bf, rois, stridep,
                                          (unsigned int*)P);
  }
  {
    dim3 grid(RNUM / 64, NBIN);
    gemm2_kernel<<<grid, 256, 0, stream>>>(P, Wt, partial);
  }
  {
    reduce_kernel<<<(RNUM * NOUT) / 256, 256, 0, stream>>>(partial, bias_mean,
                                                           out);
  }
}

// Round 9
// 99.093 us; speedup vs baseline: 6.4521x; 1.0023x over previous
//
#include <hip/hip_runtime.h>
#include <hip/hip_bf16.h>

#define HWC   2128      // H*W = 38*56
#define Hf    38
#define Wfv   56
#define CINv  1024
#define FPv   512       // FEAT_PLANES
#define RNUM  512
#define NCLSv 81
#define NOUT  85        // 81 cls + 4 loc
#define NBIN  49
#define KTOT  (NBIN * FPv)            // 25088
#define PARTN ((size_t)RNUM * NOUT)   // 43520

typedef short bf16x8 __attribute__((ext_vector_type(8)));
typedef float f32x4 __attribute__((ext_vector_type(4)));

static __device__ __forceinline__ unsigned short f2bf(float f) {
  __hip_bfloat16 h = __float2bfloat16(f);
  return *reinterpret_cast<unsigned short*>(&h);
}
static __device__ __forceinline__ float bflo(unsigned u) {
  return __uint_as_float((u & 0xffffu) << 16);
}
static __device__ __forceinline__ float bfhi(unsigned u) {
  return __uint_as_float(u & 0xffff0000u);
}

// ---------------------------------------------------------------------------
// Kernel 0 (fused prep): linear grid of 7200 blocks.
//   [0,2400):    Wt[bin][96][512] bf16 prepack (bin-major!) + bias_mean[96]
//   [2400,2912): w_new fp32 -> bf16
//   [2912,7200): feat [b][c][hw] fp32 -> featT [b][hw][c] bf16 (32x32 tiles)
// ---------------------------------------------------------------------------
__global__ __launch_bounds__(256) void prep_kernel(
    const float* __restrict__ w_score, const float* __restrict__ b_score,
    const float* __restrict__ w_bbox, const float* __restrict__ b_bbox,
    const float* __restrict__ w_new, const float* __restrict__ feat,
    unsigned short* __restrict__ Wt, float* __restrict__ bias_mean,
    unsigned short* __restrict__ wn_bf, unsigned short* __restrict__ featT) {
  __shared__ float t[32][33];
  const int bid = blockIdx.x;
  const int tid = threadIdx.x;
  if (bid >= 2912) {
    // ---- transpose+convert feat ----
    const int tb = bid - 2912;        // 0..4287
    const int bz = tb / 2144;         // batch
    const int rem = tb - bz * 2144;   // 67 x 32 tiles
    const int hw0 = (rem % 67) * 32;
    const int c0 = (rem / 67) * 32;
    const int tx = tid & 31, ty = tid >> 5;  // 32 x 8
    const float* fb = feat + (size_t)bz * CINv * HWC;
    const int hw = hw0 + tx;
#pragma unroll
    for (int i = 0; i < 4; ++i) {
      const int c = c0 + ty * 4 + i;
      t[ty * 4 + i][tx] = (hw < HWC) ? fb[(size_t)c * HWC + hw] : 0.f;
    }
    __syncthreads();
    unsigned short* ft = featT + (size_t)bz * HWC * CINv;
#pragma unroll
    for (int i = 0; i < 4; ++i) {
      const int hwo = hw0 + ty * 4 + i;
      if (hwo < HWC) ft[(size_t)hwo * CINv + c0 + tx] = f2bf(t[tx][ty * 4 + i]);
    }
    return;
  }
  if (bid >= 2400) {
    const int i = ((bid - 2400) * 256 + tid) * 4;  // < 512*1024
    const float4 v = *(const float4*)(w_new + i);
    ushort4 o;
    o.x = f2bf(v.x); o.y = f2bf(v.y); o.z = f2bf(v.z); o.w = f2bf(v.w);
    *(ushort4*)(wn_bf + i) = o;
    return;
  }
  const int c = bid % 96;
  const int by = bid / 96;  // 0..24
  if (by == 0 && tid == 0) {
    float s = 0.f;
    if (c < NCLSv)
      for (int b = 0; b < NBIN; ++b) s += b_score[c * NBIN + b];
    else if (c < NOUT)
      for (int b = 0; b < NBIN; ++b) s += b_bbox[(c - NCLSv) * NBIN + b];
    bias_mean[c] = s * (1.0f / NBIN);
  }
  const int k0 = by * 1024 + tid * 4;
  if (k0 >= KTOT) return;
  const int bin = k0 >> 9, f = k0 & 511;
  float4 v = make_float4(0.f, 0.f, 0.f, 0.f);
  if (c < NCLSv)
    v = *(const float4*)(w_score + ((size_t)(c * NBIN + bin)) * FPv + f);
  else if (c < NOUT)
    v = *(const float4*)(w_bbox + ((size_t)((c - NCLSv) * NBIN + bin)) * FPv + f);
  ushort4 o;
  o.x = f2bf(v.x); o.y = f2bf(v.y); o.z = f2bf(v.z); o.w = f2bf(v.w);
  // bin-major: Wt[bin][c][f]
  *(ushort4*)(Wt + ((size_t)bin * 96 + c) * FPv + f) = o;
}

// ---------------------------------------------------------------------------
// Kernel 1: MFMA GEMM v3: x_bf[b][hw][f] = sum_c featT[b][hw][c]*wn_bf[f][c].
// (unchanged from round 8)
// ---------------------------------------------------------------------------
#define BSTRIDE1 136
__global__ __launch_bounds__(256) void gemm1_mfma_kernel(
    const unsigned short* __restrict__ featT,
    const unsigned short* __restrict__ wn_bf,
    unsigned short* __restrict__ x_bf) {
  __shared__ unsigned short Bs[32 * BSTRIDE1];  // 8.7 KB
  const int tid = threadIdx.x;
  const int lane = tid & 63, wid = tid >> 6;
  const int b = blockIdx.z;
  const int f0 = blockIdx.y * 32;
  const int hwbase = blockIdx.x * 64 + wid * 16;
  const int arow = min(hwbase + (lane & 15), HWC - 1);
  const int fr_f = lane & 15;
  const int fr_k = (lane >> 4) << 3;
  const unsigned short* Ap = featT + ((size_t)b * HWC + arow) * CINv + fr_k;
  const int sr = tid >> 3;
  const int sc = (tid & 7) * 16;
  const unsigned short* Bg = wn_bf + (size_t)(f0 + sr) * CINv + sc;

  uint4 breg[2];
  bf16x8 aCur[4], aNxt[4];
  breg[0] = *(const uint4*)(Bg);
  breg[1] = *(const uint4*)(Bg + 8);
#pragma unroll
  for (int s = 0; s < 4; ++s) aCur[s] = *(const bf16x8*)(Ap + s * 32);

  f32x4 acc[2] = {};
  for (int kc = 0; kc < CINv; kc += 128) {
    __syncthreads();
    *(uint4*)&Bs[sr * BSTRIDE1 + sc] = breg[0];
    *(uint4*)&Bs[sr * BSTRIDE1 + sc + 8] = breg[1];
    const int kn = kc + 128;
    if (kn < CINv) {
      breg[0] = *(const uint4*)(Bg + kn);
      breg[1] = *(const uint4*)(Bg + kn + 8);
#pragma unroll
      for (int s = 0; s < 4; ++s) aNxt[s] = *(const bf16x8*)(Ap + kn + s * 32);
    }
    __syncthreads();
#pragma unroll
    for (int s = 0; s < 4; ++s) {
#pragma unroll
      for (int n = 0; n < 2; ++n) {
        const bf16x8 bv =
            *(const bf16x8*)&Bs[(fr_f + n * 16) * BSTRIDE1 + s * 32 + fr_k];
        acc[n] =
            __builtin_amdgcn_mfma_f32_16x16x32_bf16(aCur[s], bv, acc[n], 0, 0, 0);
      }
    }
#pragma unroll
    for (int s = 0; s < 4; ++s) aCur[s] = aNxt[s];
  }
  const int c_lo = lane & 15;
  const int rbase = hwbase + ((lane >> 4) << 2);
#pragma unroll
  for (int n = 0; n < 2; ++n) {
#pragma unroll
    for (int reg = 0; reg < 4; ++reg) {
      const int hwo = rbase + reg;
      if (hwo < HWC)
        x_bf[((size_t)b * HWC + hwo) * FPv + f0 + n * 16 + c_lo] =
            f2bf(acc[n][reg]);
    }
  }
}

// ---------------------------------------------------------------------------
// Kernel 2: PSRoI pooling -> P[bin][r][f] (bin-major, bf16 pairs).
// Grid (512 rois, 7 ph).
// ---------------------------------------------------------------------------
__global__ __launch_bounds__(256) void pool_kernel(
    const unsigned short* __restrict__ x_bf, const float* __restrict__ rois,
    const void* __restrict__ stride_ptr, unsigned int* __restrict__ P_u) {
  __shared__ int ys0[2], ys1[2];
  __shared__ float wys[2];
  __shared__ int xs0[14], xs1[14];
  __shared__ float wxs[14];
  const int tid = threadIdx.x;
  const int r = blockIdx.x;
  const int ph = blockIdx.y;  // 0..6
  const float* ro = rois + (size_t)r * 5;

  float stride_f;
  {
    const int iv = ((const int*)stride_ptr)[0];
    if (iv >= 1 && iv <= 4096) stride_f = (float)iv;
    else stride_f = ((const float*)stride_ptr)[0];
  }
  const float inv = 1.0f / stride_f;

  if (tid < 2) {
    const float y1v = ro[2] * inv, y2v = ro[4] * inv;
    const float bhf = fmaxf(y2v - y1v, 0.1f) * (1.0f / 7.0f);
    const int sy = tid;
    float yy = y1v + ((float)ph + ((float)sy + 0.5f) * 0.5f) * bhf;
    yy = fminf(fmaxf(yy, 0.f), (float)(Hf - 1));
    const float y0f = floorf(yy);
    ys0[tid] = (int)y0f;
    ys1[tid] = min((int)y0f + 1, Hf - 1);
    wys[tid] = yy - y0f;
  } else if (tid >= 64 && tid < 78) {
    const int s = tid - 64;
    const float x1v = ro[1] * inv, x2v = ro[3] * inv;
    const float bwf = fmaxf(x2v - x1v, 0.1f) * (1.0f / 7.0f);
    const int pw = s >> 1, sx = s & 1;
    float xx = x1v + ((float)pw + ((float)sx + 0.5f) * 0.5f) * bwf;
    xx = fminf(fmaxf(xx, 0.f), (float)(Wfv - 1));
    const float x0f = floorf(xx);
    xs0[s] = (int)x0f;
    xs1[s] = min((int)x0f + 1, Wfv - 1);
    wxs[s] = xx - x0f;
  }
  __syncthreads();

  const int b = (int)ro[0];
  const unsigned short* xb = x_bf + (size_t)b * HWC * FPv;
  const int f2 = tid * 2;

  float acc[7][2] = {};
#pragma unroll
  for (int sy = 0; sy < 2; ++sy) {
    const int ry0 = ys0[sy] * Wfv;
    const int ry1 = ys1[sy] * Wfv;
    const float wy = wys[sy];
    const float cy = 1.f - wy;
#pragma unroll
    for (int pwsx = 0; pwsx < 14; ++pwsx) {
      const int xi0 = xs0[pwsx], xi1 = xs1[pwsx];
      const float wx = wxs[pwsx];
      const float cx = 1.f - wx;
      const unsigned u00 = *(const unsigned*)(xb + (size_t)(ry0 + xi0) * FPv + f2);
      const unsigned u01 = *(const unsigned*)(xb + (size_t)(ry0 + xi1) * FPv + f2);
      const unsigned u10 = *(const unsigned*)(xb + (size_t)(ry1 + xi0) * FPv + f2);
      const unsigned u11 = *(const unsigned*)(xb + (size_t)(ry1 + xi1) * FPv + f2);
      const float w00 = cy * cx, w01 = cy * wx, w10 = wy * cx, w11 = wy * wx;
      const int pw = pwsx >> 1;
      acc[pw][0] += w00 * bflo(u00) + w01 * bflo(u01) + w10 * bflo(u10) + w11 * bflo(u11);
      acc[pw][1] += w00 * bfhi(u00) + w01 * bfhi(u01) + w10 * bfhi(u10) + w11 * bfhi(u11);
    }
  }
  // bin-major: P[bin][r][f], bin = ph*7+pw
#pragma unroll
  for (int pw = 0; pw < 7; ++pw) {
    const unsigned lo = f2bf(acc[pw][0] * 0.25f);
    const unsigned hi = f2bf(acc[pw][1] * 0.25f);
    P_u[((size_t)(ph * 7 + pw) * RNUM + r) * (FPv / 2) + tid] = lo | (hi << 16);
  }
}

// ---------------------------------------------------------------------------
// Kernel 3: MFMA GEMM, split-K by bin: partial[bin][r][c] = P[r]·Wt[c] (bin).
// Bin-major operands: A slab P[bin][64r][512], B slab Wt[bin][96][512] —
// both contiguous streams.
// ---------------------------------------------------------------------------
#define B2STRIDE 136
__global__ __launch_bounds__(256) void gemm2_kernel(
    const unsigned short* __restrict__ P, const unsigned short* __restrict__ Wt,
    float* __restrict__ partial) {
  __shared__ unsigned short Bs[96 * B2STRIDE];
  const int tid = threadIdx.x;
  const int lane = tid & 63, wid = tid >> 6;
  const int rt = blockIdx.x;   // 0..7
  const int bin = blockIdx.y;  // 0..48
  const int arow = rt * 64 + wid * 16 + (lane & 15);
  const int fr_f = lane & 15;
  const int fr_k = (lane >> 4) << 3;
  const unsigned short* Ap = P + ((size_t)bin * RNUM + arow) * FPv + fr_k;
  int srow[3], scol[3];
#pragma unroll
  for (int g = 0; g < 3; ++g) {
    const int idx = tid * 48 + g * 16;
    srow[g] = idx >> 7;
    scol[g] = idx & 127;
  }
  const unsigned short* WtB = Wt + (size_t)bin * 96 * FPv;

  uint4 breg[6];
  bf16x8 aCur[4], aNxt[4];
#pragma unroll
  for (int g = 0; g < 3; ++g) {
    const unsigned short* src = WtB + (size_t)srow[g] * FPv + scol[g];
    breg[g * 2] = *(const uint4*)src;
    breg[g * 2 + 1] = *(const uint4*)(src + 8);
  }
#pragma unroll
  for (int s = 0; s < 4; ++s) aCur[s] = *(const bf16x8*)(Ap + s * 32);

  f32x4 acc[6] = {};
  for (int kc = 0; kc < FPv; kc += 128) {
    __syncthreads();
#pragma unroll
    for (int g = 0; g < 3; ++g) {
      unsigned short* dst = &Bs[srow[g] * B2STRIDE + scol[g]];
      *(uint4*)dst = breg[g * 2];
      *(uint4*)(dst + 8) = breg[g * 2 + 1];
    }
    const int kn = kc + 128;
    if (kn < FPv) {
#pragma unroll
      for (int g = 0; g < 3; ++g) {
        const unsigned short* src = WtB + (size_t)srow[g] * FPv + kn + scol[g];
        breg[g * 2] = *(const uint4*)src;
        breg[g * 2 + 1] = *(const uint4*)(src + 8);
      }
#pragma unroll
      for (int s = 0; s < 4; ++s) aNxt[s] = *(const bf16x8*)(Ap + kn + s * 32);
    }
    __syncthreads();
#pragma unroll
    for (int s = 0; s < 4; ++s) {
#pragma unroll
      for (int n = 0; n < 6; ++n) {
        const bf16x8 bv =
            *(const bf16x8*)&Bs[(fr_f + n * 16) * B2STRIDE + s * 32 + fr_k];
        acc[n] =
            __builtin_amdgcn_mfma_f32_16x16x32_bf16(aCur[s], bv, acc[n], 0, 0, 0);
      }
    }
#pragma unroll
    for (int s = 0; s < 4; ++s) aCur[s] = aNxt[s];
  }
  const int c_lo = lane & 15;
  const int rr = rt * 64 + wid * 16 + ((lane >> 4) << 2);
  float* pb = partial + (size_t)bin * PARTN;
#pragma unroll
  for (int n = 0; n < 6; ++n) {
    const int c = n * 16 + c_lo;
    if (c < NOUT) {
#pragma unroll
      for (int reg = 0; reg < 4; ++reg)
        pb[(size_t)(rr + reg) * NOUT + c] = acc[n][reg];
    }
  }
}

// ---------------------------------------------------------------------------
// Kernel 4: fixed-order reduction over 49 bins + bias -> final layout.
// ---------------------------------------------------------------------------
__global__ __launch_bounds__(256) void reduce_kernel(
    const float* __restrict__ partial, const float* __restrict__ bias_mean,
    float* __restrict__ out) {
  const int g = blockIdx.x * 256 + threadIdx.x;  // 0..43519
  const int r = g / NOUT;
  const int cc = g - r * NOUT;
  float s = 0.f;
  for (int b = 0; b < NBIN; ++b) s += partial[(size_t)b * PARTN + g];
  s = s * (1.0f / NBIN) + bias_mean[cc];
  if (cc < NCLSv)
    out[(size_t)r * NCLSv + cc] = s;
  else
    out[(size_t)RNUM * NCLSv + (size_t)r * 4 + (cc - NCLSv)] = s;
}

// ---------------------------------------------------------------------------
extern "C" void kernel_launch(void* const* d_in, const int* in_sizes, int n_in,
                              void* d_out, int out_size, void* d_ws,
                              size_t ws_size, hipStream_t stream) {
  const float* rois    = (const float*)d_in[0];
  const float* feat    = (const float*)d_in[1];
  const float* w_new   = (const float*)d_in[2];
  const float* w_score = (const float*)d_in[3];
  const float* b_score = (const float*)d_in[4];
  const float* w_bbox  = (const float*)d_in[5];
  const float* b_bbox  = (const float*)d_in[6];
  const void*  stridep = d_in[7];
  float* out = (float*)d_out;

  // ws layout (256B-aligned). featT (dead after gemm1) aliases partial.
  char* w = (char*)d_ws;
  unsigned short* x_bf = (unsigned short*)w;               // 4,358,144 B
  w += ((size_t)2 * HWC * FPv * 2 + 255) & ~(size_t)255;
  unsigned short* P = (unsigned short*)w;                  // 25,690,112 B
  w += ((size_t)RNUM * KTOT * 2 + 255) & ~(size_t)255;
  unsigned short* Wt = (unsigned short*)w;                 // 4,816,896 B
  w += ((size_t)96 * KTOT * 2 + 255) & ~(size_t)255;
  char* shared_blk = w;                                    // max(featT, partial)
  unsigned short* featT = (unsigned short*)shared_blk;     // 8,716,288 B
  float* partial = (float*)shared_blk;                     // 8,529,920 B
  w += ((size_t)2 * HWC * CINv * 2 + 255) & ~(size_t)255;
  unsigned short* wn_bf = (unsigned short*)w;              // 1,048,576 B
  w += ((size_t)FPv * CINv * 2 + 255) & ~(size_t)255;
  float* bias_mean = (float*)w;                            // 384 B

  {
    prep_kernel<<<7200, 256, 0, stream>>>(w_score, b_score, w_bbox, b_bbox,
                                          w_new, feat, Wt, bias_mean, wn_bf,
                                          featT);
  }
  {
    dim3 grid((HWC + 63) / 64, FPv / 32, 2);
    gemm1_mfma_kernel<<<grid, 256, 0, stream>>>(featT, wn_bf, x_bf);
  }
  {
    dim3 grid(RNUM, 7);
    pool_kernel<<<grid, 256, 0, stream>>>(x_bf, rois, stridep,
                                          (unsigned int*)P);
  }
  {
    dim3 grid(RNUM / 64, NBIN);
    gemm2_kernel<<<grid, 256, 0, stream>>>(P, Wt, partial);
  }
  {
    reduce_kernel<<<(RNUM * NOUT) / 256, 256, 0, stream>>>(partial, bias_mean,
                                                           out);
  }
}